// Round 8
// baseline (2842.591 us; speedup 1.0000x reference)
//
#include <hip/hip_runtime.h>

// Problem dims
#define B_ 32
#define S_ 512
#define D_ 512
#define H_ 256

typedef float floatx4 __attribute__((ext_vector_type(4)));
typedef short short8v __attribute__((ext_vector_type(8)));
typedef int intx4 __attribute__((ext_vector_type(4)));
typedef unsigned short u16;
typedef unsigned int u32;
typedef unsigned long long u64;

#define WS_NEEDED 138575872ull

__device__ __forceinline__ u16 f2bf(float f) {
  u32 x = __float_as_uint(f);
  x += 0x7fffu + ((x >> 16) & 1u);   // RNE
  return (u16)(x >> 16);
}
__device__ __forceinline__ float bf2f(u16 h) {
  return __uint_as_float(((u32)h) << 16);
}
__device__ __forceinline__ float decode_hl(u32 v) {
  return bf2f((u16)(v >> 16)) + bf2f((u16)(v & 0xffffu));
}
__device__ __forceinline__ float sigf(float x) {
  return 1.0f / (1.0f + __expf(-x));
}
__device__ __forceinline__ float tanh_f(float x) {
  float e = __expf(-2.0f * fabsf(x));
  float r = (1.0f - e) / (1.0f + e);
  return copysignf(r, x);
}

struct alignas(16) U16x8 { u16 v[8]; };

// ---------------- embedding -> X0 bf16, time-major (m = s*32+b, 512 feats) ----------------
__global__ void prep_k(const int* __restrict__ ids, const int* __restrict__ amask,
                       const float* __restrict__ emb, u16* __restrict__ X0) {
  int m = blockIdx.x;            // m = s*32 + b
  int lane = threadIdx.x;        // 64
  int s = m >> 5, b = m & 31;
  int id = ids[b * S_ + s];
  int mk = amask[b * S_ + s];
  const float4* src = (const float4*)(emb + (size_t)id * D_) + lane * 2;
  float4 v0 = src[0], v1 = src[1];
  if (!mk) { v0 = make_float4(0,0,0,0); v1 = make_float4(0,0,0,0); }
  U16x8 o;
  o.v[0]=f2bf(v0.x); o.v[1]=f2bf(v0.y); o.v[2]=f2bf(v0.z); o.v[3]=f2bf(v0.w);
  o.v[4]=f2bf(v1.x); o.v[5]=f2bf(v1.y); o.v[6]=f2bf(v1.z); o.v[7]=f2bf(v1.w);
  *(U16x8*)(X0 + (size_t)m * D_ + lane * 8) = o;
}

// ---------------- fp32 -> bf16 weight convert (w_ih, 2*2*1024*512 elems) ----------------
__global__ void conv_k(const float* __restrict__ w, u16* __restrict__ wbf, int n8) {
  int idx = blockIdx.x * blockDim.x + threadIdx.x;
  if (idx >= n8) return;
  const float4* s = (const float4*)w + (size_t)idx * 2;
  float4 v0 = s[0], v1 = s[1];
  U16x8 o;
  o.v[0]=f2bf(v0.x); o.v[1]=f2bf(v0.y); o.v[2]=f2bf(v0.z); o.v[3]=f2bf(v0.w);
  o.v[4]=f2bf(v1.x); o.v[5]=f2bf(v1.y); o.v[6]=f2bf(v1.z); o.v[7]=f2bf(v1.w);
  *(U16x8*)(wbf + (size_t)idx * 8) = o;
}

// ---------------- zero loss ----------------
__global__ void zero_k(float* __restrict__ loss) {
  if (threadIdx.x == 0) *loss = 0.f;
}

// ---------------- w_hh fp32 -> per-row-scaled i8 (4096 rows of 256) ----------------
// w = s_row*q, q=rint(w/s_row) in [-127,127]; wsc[r] = s_row/127 (h's 1/127 folded in):
// gate_rec = sum(w*h) ~ wsc[r] * sum(qw*qh) with qh = rint(h*127).
__global__ void convw_k(const float* __restrict__ whh, signed char* __restrict__ wq,
                        float* __restrict__ wsc) {
  const int r = blockIdx.x;          // 0..4095 = (layer,dir,gate-row)
  const int lane = threadIdx.x;      // 64
  float4 v = *(const float4*)(whh + (size_t)r * 256 + lane * 4);
  float m = fmaxf(fmaxf(fabsf(v.x), fabsf(v.y)), fmaxf(fabsf(v.z), fabsf(v.w)));
  #pragma unroll
  for (int off = 32; off > 0; off >>= 1) m = fmaxf(m, __shfl_xor(m, off, 64));
  const float s = fmaxf(m, 1e-20f) * (1.0f / 127.0f);
  const float inv = 1.0f / s;
  int q0 = (int)rintf(v.x * inv), q1 = (int)rintf(v.y * inv);
  int q2 = (int)rintf(v.z * inv), q3 = (int)rintf(v.w * inv);
  u32 pk = (u32)(q0 & 255) | ((u32)(q1 & 255) << 8)
         | ((u32)(q2 & 255) << 16) | ((u32)(q3 & 255) << 24);
  *(u32*)(wq + (size_t)r * 256 + lane * 4) = pk;
  if (lane == 0) wsc[r] = s * (1.0f / 127.0f);
}

// ---------------- bf16 MFMA GEMM: G[m][n] = A[m][:] . W[n][:] + bih[n] + bhh[n] ----------------
__global__ void gemm_k(const u16* __restrict__ A, const u16* __restrict__ W,
                       const float* __restrict__ bih, const float* __restrict__ bhh,
                       u16* __restrict__ G) {
  __shared__ short Asm[64 * 40];
  __shared__ short Bsm[64 * 40];
  const int tid = threadIdx.x;
  const int m0 = blockIdx.x * 64, n0 = blockIdx.y * 64;
  const int wid = tid >> 6, lane = tid & 63;
  const int quad = lane >> 4, lr = lane & 15;
  const int wm = (wid >> 1) * 32, wn = (wid & 1) * 32;
  const int lrow = tid >> 2, lk = (tid & 3) * 8;
  floatx4 acc00 = {0,0,0,0}, acc01 = {0,0,0,0}, acc10 = {0,0,0,0}, acc11 = {0,0,0,0};
  for (int kt = 0; kt < 16; ++kt) {
    const int k0 = kt * 32;
    uint4 av = *(const uint4*)(A + (size_t)(m0 + lrow) * 512 + k0 + lk);
    uint4 bv = *(const uint4*)(W + (size_t)(n0 + lrow) * 512 + k0 + lk);
    __syncthreads();
    *(uint4*)&Asm[lrow * 40 + lk] = av;
    *(uint4*)&Bsm[lrow * 40 + lk] = bv;
    __syncthreads();
    short8v a0 = *(const short8v*)&Asm[(wm + lr) * 40 + quad * 8];
    short8v a1 = *(const short8v*)&Asm[(wm + 16 + lr) * 40 + quad * 8];
    short8v b0 = *(const short8v*)&Bsm[(wn + lr) * 40 + quad * 8];
    short8v b1 = *(const short8v*)&Bsm[(wn + 16 + lr) * 40 + quad * 8];
    acc00 = __builtin_amdgcn_mfma_f32_16x16x32_bf16(a0, b0, acc00, 0, 0, 0);
    acc01 = __builtin_amdgcn_mfma_f32_16x16x32_bf16(a0, b1, acc01, 0, 0, 0);
    acc10 = __builtin_amdgcn_mfma_f32_16x16x32_bf16(a1, b0, acc10, 0, 0, 0);
    acc11 = __builtin_amdgcn_mfma_f32_16x16x32_bf16(a1, b1, acc11, 0, 0, 0);
  }
  #pragma unroll
  for (int j = 0; j < 2; ++j) {
    const int n = n0 + wn + j * 16 + lr;
    const float bias = bih[n] + bhh[n];
    #pragma unroll
    for (int i = 0; i < 2; ++i) {
      const int mb = m0 + wm + i * 16 + quad * 4;
      floatx4 av = (i == 0) ? (j == 0 ? acc00 : acc01) : (j == 0 ? acc10 : acc11);
      #pragma unroll
      for (int rr = 0; rr < 4; ++rr) {
        G[(size_t)(mb + rr) * 2048 + n] = f2bf(av[rr] + bias);
      }
    }
  }
}

// ---------------- LSTM recurrence: FULLY BLOCK-LOCAL (no cross-CU exchange) ----------------
// v8: partition over BATCH, not hidden. 8 blocks = dir(2) x bg(4); each block owns
// ALL 256 hidden for its 8 batches -> the recurrence closes through LDS; the
// ~5000-cycle store->LLC->poll round trip (measured invariant of v1..v7) is GONE.
// This fits because Whh is i8 per-row-scaled: 4g x 256h x 256k x 1B = 256 KB =
// 128 VGPRs/wave across 8 waves (512 thr, 2 waves/SIMD @ 256 VGPR).
// Wave w owns hidden chunk [w*32, w*32+32), all 4 gates = 8 row-tiles of 16.
// MFMA i32_16x16x64_i8: A = weight tile (regs), B = i8-quantized h from LDS
// (hq[batch][k]); C col = batch (lane&15), row = q*4+reg. Lanes c<8 update
// sub-tile 0 cells, lanes c>=8 take sub-tile 1 via shfl_xor(8). Cell update is
// in-register (gate = bf16 G + acc*wsc_row); h stays full-precision bf16/hi-lo
// on the X path (written straight to global, 64B-line-coalesced per (w,b) -
// no X staging LDS at all). G prefetched 3 deep (step << HBM latency now).
__launch_bounds__(512, 2)
__global__ void rec_k(const u16* __restrict__ G, const signed char* __restrict__ wq_l,
                      const float* __restrict__ wsc_l,
                      u16* __restrict__ Xbf, u32* __restrict__ Xu) {
  __shared__ signed char hq[2][16][256];   // [parity][batch][k]; rows 8..15 stay 0

  const int tid = threadIdx.x;
  const int dir = blockIdx.x >> 2;
  const int bg = blockIdx.x & 3;
  const int w = tid >> 6;        // wave = hidden chunk w*32
  const int lane = tid & 63;
  const int q = lane >> 4;
  const int c = lane & 15;       // batch col in the MFMA C layout
  const int b = c & 7;           // real batch in group
  const int myS = c >> 3;        // sub-tile (16 hidden) this lane updates

  const signed char* wq = wq_l + (size_t)dir * 262144;
  const float* wsc = wsc_l + (size_t)dir * 1024;

  // ---- one-time: A-fragments (i8 weights) + per-cell scales ----
  intx4 A[4][2][4];   // [gate][sub][ktile] : 16 i8 = 4 VGPR each -> 128 VGPR
  #pragma unroll
  for (int g = 0; g < 4; ++g)
    #pragma unroll
    for (int s_ = 0; s_ < 2; ++s_) {
      const int row = g * 256 + w * 32 + s_ * 16 + c;   // A row = lane&15
      #pragma unroll
      for (int kt = 0; kt < 4; ++kt)
        A[g][s_][kt] = *(const intx4*)(wq + (size_t)row * 256 + kt * 64 + q * 16);
    }
  float sc0[4], sc1[4], sc2[4], sc3[4];   // row scales for THIS lane's 4 cells
  #pragma unroll
  for (int reg = 0; reg < 4; ++reg) {
    const int hrow = w * 32 + myS * 16 + q * 4 + reg;
    sc0[reg] = wsc[0 * 256 + hrow];
    sc1[reg] = wsc[1 * 256 + hrow];
    sc2[reg] = wsc[2 * 256 + hrow];
    sc3[reg] = wsc[3 * 256 + hrow];
  }
  if (tid < 512) ((uint4*)hq)[tid] = make_uint4(0, 0, 0, 0);  // 8 KB zero-init
  float cst[4] = {0.f, 0.f, 0.f, 0.f};

  // G for this lane's cells: 4 gates x 4 consecutive hidden, batch b
  const u16* gb_ = G + (size_t)(bg * 8 + b) * 2048 + dir * 1024
                 + w * 32 + myS * 16 + q * 4;
  // 3-deep G prefetch (step time << HBM latency)
  u64 gc[4], g1[4], g2[4];
  #pragma unroll
  for (int pf = 0; pf < 3; ++pf) {
    const int tn = dir ? (511 - pf) : pf;
    const u16* gp = gb_ + (size_t)tn * 65536;    // 32*2048 u16 per step
    u64* dst = (pf == 0) ? gc : (pf == 1) ? g1 : g2;
    dst[0] = *(const u64*)(gp);
    dst[1] = *(const u64*)(gp + 256);
    dst[2] = *(const u64*)(gp + 512);
    dst[3] = *(const u64*)(gp + 768);
  }
  __syncthreads();

  for (int st = 0; st < 512; ++st) {
    const int par = st & 1;
    // B-fragments: i8 h of this step (col = batch c, k-chunk = q)
    intx4 bf0 = *(const intx4*)&hq[par][c][0 * 64 + q * 16];
    intx4 bf1 = *(const intx4*)&hq[par][c][1 * 64 + q * 16];
    intx4 bf2 = *(const intx4*)&hq[par][c][2 * 64 + q * 16];
    intx4 bf3 = *(const intx4*)&hq[par][c][3 * 64 + q * 16];
    // MFMA: acc[g][sub] = Whh[g,sub-tile] . h  (int32)
    intx4 acc[4][2];
    #pragma unroll
    for (int g = 0; g < 4; ++g)
      #pragma unroll
      for (int s_ = 0; s_ < 2; ++s_) {
        intx4 a_ = {0, 0, 0, 0};
        a_ = __builtin_amdgcn_mfma_i32_16x16x64_i8(A[g][s_][0], bf0, a_, 0, 0, 0);
        a_ = __builtin_amdgcn_mfma_i32_16x16x64_i8(A[g][s_][1], bf1, a_, 0, 0, 0);
        a_ = __builtin_amdgcn_mfma_i32_16x16x64_i8(A[g][s_][2], bf2, a_, 0, 0, 0);
        a_ = __builtin_amdgcn_mfma_i32_16x16x64_i8(A[g][s_][3], bf3, a_, 0, 0, 0);
        acc[g][s_] = a_;
      }
    // cell update: 4 cells/lane; lanes c>=8 take sub=1 accs from lane c-8
    u16 hb16[4]; float hfv[4];
    #pragma unroll
    for (int reg = 0; reg < 4; ++reg) {
      const int v0 = __shfl_xor(acc[0][1][reg], 8, 64);
      const int v1 = __shfl_xor(acc[1][1][reg], 8, 64);
      const int v2 = __shfl_xor(acc[2][1][reg], 8, 64);
      const int v3 = __shfl_xor(acc[3][1][reg], 8, 64);
      const float gr0 = (float)((c < 8) ? acc[0][0][reg] : v0) * sc0[reg];
      const float gr1 = (float)((c < 8) ? acc[1][0][reg] : v1) * sc1[reg];
      const float gr2 = (float)((c < 8) ? acc[2][0][reg] : v2) * sc2[reg];
      const float gr3 = (float)((c < 8) ? acc[3][0][reg] : v3) * sc3[reg];
      const float si = bf2f((u16)(gc[0] >> (16 * reg))) + gr0;
      const float sf = bf2f((u16)(gc[1] >> (16 * reg))) + gr1;
      const float sg = bf2f((u16)(gc[2] >> (16 * reg))) + gr2;
      const float so = bf2f((u16)(gc[3] >> (16 * reg))) + gr3;
      const float ig = sigf(si), fg = sigf(sf), gg = tanh_f(sg), og = sigf(so);
      const float cn = fg * cst[reg] + ig * gg;
      const float hn = og * tanh_f(cn);
      cst[reg] = cn;
      hfv[reg] = hn;
      hb16[reg] = f2bf(hn);
    }
    // quantize h -> i8, write to next-parity LDS (unique u32 per lane)
    {
      const int q0 = (int)rintf(hfv[0] * 127.f);
      const int q1 = (int)rintf(hfv[1] * 127.f);
      const int q2 = (int)rintf(hfv[2] * 127.f);
      const int q3 = (int)rintf(hfv[3] * 127.f);
      const u32 qpk = (u32)(q0 & 255) | ((u32)(q1 & 255) << 8)
                    | ((u32)(q2 & 255) << 16) | ((u32)(q3 & 255) << 24);
      *(u32*)&hq[par ^ 1][b][w * 32 + myS * 16 + q * 4] = qpk;
    }
    // X output: direct global write (8 lanes of a (w,b) pair cover one 64B line)
    {
      const int tt = dir ? (511 - st) : st;
      const size_t xo = ((size_t)tt * 32 + bg * 8 + b) * 512 + dir * 256
                      + w * 32 + myS * 16 + q * 4;
      if (Xbf) {
        u64 xv = (u64)hb16[0] | ((u64)hb16[1] << 16)
               | ((u64)hb16[2] << 32) | ((u64)hb16[3] << 48);
        *(u64*)(Xbf + xo) = xv;
      } else {
        uint4 xv;
        xv.x = ((u32)hb16[0] << 16) | f2bf(hfv[0] - bf2f(hb16[0]));
        xv.y = ((u32)hb16[1] << 16) | f2bf(hfv[1] - bf2f(hb16[1]));
        xv.z = ((u32)hb16[2] << 16) | f2bf(hfv[2] - bf2f(hb16[2]));
        xv.w = ((u32)hb16[3] << 16) | f2bf(hfv[3] - bf2f(hb16[3]));
        *(uint4*)(Xu + xo) = xv;
      }
    }
    // rotate G prefetch window (consume st; hold st+1, st+2; issue st+3)
    #pragma unroll
    for (int g = 0; g < 4; ++g) { gc[g] = g1[g]; g1[g] = g2[g]; }
    {
      const int stn = (st + 3 < 512) ? st + 3 : 511;
      const int tn = dir ? (511 - stn) : stn;
      const u16* gp = gb_ + (size_t)tn * 65536;
      g2[0] = *(const u64*)(gp);
      g2[1] = *(const u64*)(gp + 256);
      g2[2] = *(const u64*)(gp + 512);
      g2[3] = *(const u64*)(gp + 768);
    }
    __syncthreads();   // h(par^1) visible to all waves for step st+1
  }
}

// ---------------- LayerNorm + classifier head; logits -> d_out+1 ----------------
// X2u: packed (bf16hi<<16|bf16lo) per element; decode = bf2f(hi)+bf2f(lo)
__global__ void head_k(const u32* __restrict__ X2u, const float* __restrict__ gamma,
                       const float* __restrict__ beta, const float* __restrict__ cw,
                       const float* __restrict__ cb, float* __restrict__ out) {
  __shared__ float red[9][64];
  const int m = blockIdx.x, lane = threadIdx.x;
  const int s = m >> 5, b = m & 31;
  const uint4* xp = (const uint4*)(X2u + (size_t)m * 512) + lane * 2;
  uint4 a0 = xp[0], a1 = xp[1];
  float x[8];
  x[0] = decode_hl(a0.x); x[1] = decode_hl(a0.y);
  x[2] = decode_hl(a0.z); x[3] = decode_hl(a0.w);
  x[4] = decode_hl(a1.x); x[5] = decode_hl(a1.y);
  x[6] = decode_hl(a1.z); x[7] = decode_hl(a1.w);
  float sm = 0.f, sq = 0.f;
  #pragma unroll
  for (int i = 0; i < 8; ++i) { sm += x[i]; sq += x[i] * x[i]; }
  #pragma unroll
  for (int off = 32; off > 0; off >>= 1) {
    sm += __shfl_xor(sm, off, 64);
    sq += __shfl_xor(sq, off, 64);
  }
  const float mu = sm * (1.0f / 512.0f);
  const float var = sq * (1.0f / 512.0f) - mu * mu;
  const float rs = rsqrtf(var + 1e-5f);
  const float4* gp = (const float4*)gamma + lane * 2;
  const float4* bp = (const float4*)beta + lane * 2;
  float4 g0 = gp[0], g1 = gp[1], be0 = bp[0], be1 = bp[1];
  float nv[8];
  nv[0] = (x[0] - mu) * rs * g0.x + be0.x;
  nv[1] = (x[1] - mu) * rs * g0.y + be0.y;
  nv[2] = (x[2] - mu) * rs * g0.z + be0.z;
  nv[3] = (x[3] - mu) * rs * g0.w + be0.w;
  nv[4] = (x[4] - mu) * rs * g1.x + be1.x;
  nv[5] = (x[5] - mu) * rs * g1.y + be1.y;
  nv[6] = (x[6] - mu) * rs * g1.z + be1.z;
  nv[7] = (x[7] - mu) * rs * g1.w + be1.w;
  #pragma unroll
  for (int c = 0; c < 9; ++c) {
    const float4* wp = (const float4*)(cw + (size_t)c * 512) + lane * 2;
    float4 w0 = wp[0], w1 = wp[1];
    red[c][lane] = nv[0]*w0.x + nv[1]*w0.y + nv[2]*w0.z + nv[3]*w0.w
                 + nv[4]*w1.x + nv[5]*w1.y + nv[6]*w1.z + nv[7]*w1.w;
  }
  __syncthreads();
  if (lane < 9) {
    float t = 0.f;
    for (int i = 0; i < 64; ++i) t += red[lane][i];
    out[1 + ((size_t)b * 512 + s) * 9 + lane] = t + cb[lane];
  }
}

// ---------------- CRF NLL: one wave per batch element ----------------
__global__ void crf_k(const float* __restrict__ logits, const int* __restrict__ labels,
                      const int* __restrict__ lens, const float* __restrict__ tr,
                      float* __restrict__ loss) {
  const int b = blockIdx.x, lane = threadIdx.x;
  const int len = lens[b];
  float trj[9];
  #pragma unroll
  for (int i = 0; i < 9; ++i) trj[i] = 0.f;
  if (lane < 9) {
    #pragma unroll
    for (int i = 0; i < 9; ++i) trj[i] = tr[i * 11 + lane];
  }
  float alpha = -1e30f;
  if (lane < 9) alpha = tr[9 * 11 + lane] + logits[(size_t)b * 512 * 9 + lane];
  for (int t = 1; t < len; ++t) {
    float e = (lane < 9) ? logits[((size_t)b * 512 + t) * 9 + lane] : 0.f;
    float v[9];
    float mx = -1e30f;
    #pragma unroll
    for (int i = 0; i < 9; ++i) {
      v[i] = __shfl(alpha, i, 64) + trj[i];
      mx = fmaxf(mx, v[i]);
    }
    float ss = 0.f;
    #pragma unroll
    for (int i = 0; i < 9; ++i) ss += __expf(v[i] - mx);
    float na = mx + __logf(ss) + e;
    if (lane < 9) alpha = na;
  }
  float fin = (lane < 9) ? alpha + tr[lane * 11 + 10] : -1e30f;
  float mx = fin;
  #pragma unroll
  for (int off = 8; off > 0; off >>= 1) mx = fmaxf(mx, __shfl_xor(mx, off, 64));
  float es = (lane < 9) ? __expf(fin - mx) : 0.f;
  #pragma unroll
  for (int off = 8; off > 0; off >>= 1) es += __shfl_xor(es, off, 64);
  const float logZ = mx + __logf(es);
  float emit = 0.f, ts = 0.f;
  for (int t = lane; t < len; t += 64) {
    int y = labels[b * 512 + t];
    emit += logits[((size_t)b * 512 + t) * 9 + y];
  }
  for (int t = 1 + lane; t < len; t += 64) {
    int y0 = labels[b * 512 + t - 1], y1 = labels[b * 512 + t];
    ts += tr[y0 * 11 + y1];
  }
  #pragma unroll
  for (int off = 32; off > 0; off >>= 1) {
    emit += __shfl_xor(emit, off, 64);
    ts += __shfl_xor(ts, off, 64);
  }
  if (lane == 0) {
    int y0 = labels[b * 512], yl = labels[b * 512 + len - 1];
    float gold = emit + ts + tr[9 * 11 + y0] + tr[yl * 11 + 10];
    atomicAdd(loss, (logZ - gold) * (1.0f / 32.0f));
  }
}

extern "C" void kernel_launch(void* const* d_in, const int* in_sizes, int n_in,
                              void* d_out, int out_size, void* d_ws, size_t ws_size,
                              hipStream_t stream) {
  const int* ids = (const int*)d_in[0];
  const int* amask = (const int*)d_in[1];
  const int* lens = (const int*)d_in[2];
  const int* labels = (const int*)d_in[3];
  const float* emb = (const float*)d_in[4];
  const float* w_ih = (const float*)d_in[5];
  const float* w_hh = (const float*)d_in[6];
  const float* b_ih = (const float*)d_in[7];
  const float* b_hh = (const float*)d_in[8];
  const float* gamma = (const float*)d_in[9];
  const float* beta = (const float*)d_in[10];
  const float* cw = (const float*)d_in[11];
  const float* cb = (const float*)d_in[12];
  const float* tr = (const float*)d_in[13];
  (void)in_sizes; (void)n_in; (void)out_size;

  if (ws_size < WS_NEEDED) return;  // workspace too small -> clean failure

  char* p = (char*)d_ws;
  u16* X0 = (u16*)p;      p += (size_t)16384 * 512 * 2;        // 16.78 MB
  u16* Wbf = (u16*)p;     p += (size_t)2 * 2 * 1024 * 512 * 2; // 4.19 MB
  u16* G = (u16*)p;       p += (size_t)16384 * 2048 * 2;       // 67.1 MB
  u16* X1 = (u16*)p;      p += (size_t)16384 * 512 * 2;        // 16.78 MB
  u32* X2u = (u32*)p;     p += (size_t)16384 * 512 * 4;        // 33.55 MB
  float* out = (float*)d_out;

  // i8 Whh + per-row scales live in the X0 region's head, written AFTER gemm0
  // consumes X0 (X0 is dead from then on; gemm1 reads X1, rec1 writes X2u).
  signed char* Wq = (signed char*)X0;             // 4096 x 256 = 1 MB
  float* Wsc = (float*)((char*)X0 + 1048576);     // 4096 floats = 16 KB

  prep_k<<<16384, 64, 0, stream>>>(ids, amask, emb, X0);
  conv_k<<<1024, 256, 0, stream>>>(w_ih, Wbf, 262144);
  zero_k<<<1, 64, 0, stream>>>(out);
  // Layer 0
  gemm_k<<<dim3(256, 32), 256, 0, stream>>>(X0, Wbf, b_ih, b_hh, G);
  convw_k<<<4096, 64, 0, stream>>>(w_hh, Wq, Wsc);   // X0 dead after gemm0
  rec_k<<<8, 512, 0, stream>>>(G, Wq, Wsc, X1, nullptr);
  // Layer 1
  gemm_k<<<dim3(256, 32), 256, 0, stream>>>(X1, Wbf + 2 * 1024 * 512,
                                            b_ih + 2048, b_hh + 2048, G);
  rec_k<<<8, 512, 0, stream>>>(G, Wq + 2 * 262144, Wsc + 2048, nullptr, X2u);
  // Head + CRF
  head_k<<<16384, 64, 0, stream>>>(X2u, gamma, beta, cw, cb, out);
  crf_k<<<32, 64, 0, stream>>>(out + 1, labels, lens, tr, out);
}

// Round 9
// 2510.246 us; speedup vs baseline: 1.1324x; 1.1324x over previous
//
#include <hip/hip_runtime.h>

// Problem dims
#define B_ 32
#define S_ 512
#define D_ 512
#define H_ 256

typedef float floatx4 __attribute__((ext_vector_type(4)));
typedef short short8v __attribute__((ext_vector_type(8)));
typedef int intx4 __attribute__((ext_vector_type(4)));
typedef unsigned short u16;
typedef unsigned int u32;
typedef unsigned long long u64;

#define WS_NEEDED 138575872ull

__device__ __forceinline__ u16 f2bf(float f) {
  u32 x = __float_as_uint(f);
  x += 0x7fffu + ((x >> 16) & 1u);   // RNE
  return (u16)(x >> 16);
}
__device__ __forceinline__ float bf2f(u16 h) {
  return __uint_as_float(((u32)h) << 16);
}
__device__ __forceinline__ float decode_hl(u32 v) {
  return bf2f((u16)(v >> 16)) + bf2f((u16)(v & 0xffffu));
}
__device__ __forceinline__ float sigf(float x) {
  return 1.0f / (1.0f + __expf(-x));
}
__device__ __forceinline__ float tanh_f(float x) {
  float e = __expf(-2.0f * fabsf(x));
  float r = (1.0f - e) / (1.0f + e);
  return copysignf(r, x);
}

struct alignas(16) U16x8 { u16 v[8]; };

// ---------------- embedding -> X0 bf16, time-major (m = s*32+b, 512 feats) ----------------
__global__ void prep_k(const int* __restrict__ ids, const int* __restrict__ amask,
                       const float* __restrict__ emb, u16* __restrict__ X0) {
  int m = blockIdx.x;            // m = s*32 + b
  int lane = threadIdx.x;        // 64
  int s = m >> 5, b = m & 31;
  int id = ids[b * S_ + s];
  int mk = amask[b * S_ + s];
  const float4* src = (const float4*)(emb + (size_t)id * D_) + lane * 2;
  float4 v0 = src[0], v1 = src[1];
  if (!mk) { v0 = make_float4(0,0,0,0); v1 = make_float4(0,0,0,0); }
  U16x8 o;
  o.v[0]=f2bf(v0.x); o.v[1]=f2bf(v0.y); o.v[2]=f2bf(v0.z); o.v[3]=f2bf(v0.w);
  o.v[4]=f2bf(v1.x); o.v[5]=f2bf(v1.y); o.v[6]=f2bf(v1.z); o.v[7]=f2bf(v1.w);
  *(U16x8*)(X0 + (size_t)m * D_ + lane * 8) = o;
}

// ---------------- fp32 -> bf16 weight convert (w_ih, 2*2*1024*512 elems) ----------------
__global__ void conv_k(const float* __restrict__ w, u16* __restrict__ wbf, int n8) {
  int idx = blockIdx.x * blockDim.x + threadIdx.x;
  if (idx >= n8) return;
  const float4* s = (const float4*)w + (size_t)idx * 2;
  float4 v0 = s[0], v1 = s[1];
  U16x8 o;
  o.v[0]=f2bf(v0.x); o.v[1]=f2bf(v0.y); o.v[2]=f2bf(v0.z); o.v[3]=f2bf(v0.w);
  o.v[4]=f2bf(v1.x); o.v[5]=f2bf(v1.y); o.v[6]=f2bf(v1.z); o.v[7]=f2bf(v1.w);
  *(U16x8*)(wbf + (size_t)idx * 8) = o;
}

// ---------------- zero loss ----------------
__global__ void zero_k(float* __restrict__ loss) {
  if (threadIdx.x == 0) *loss = 0.f;
}

// ---------------- w_hh fp32 -> per-row-scaled i8 (4096 rows of 256) ----------------
// w = s_row*q, q=rint(w/s_row) in [-127,127]; wsc[r] = s_row/127 (h's 1/127 folded in):
// gate_rec = sum(w*h) ~ wsc[r] * sum(qw*qh) with qh = rint(h*127).
__global__ void convw_k(const float* __restrict__ whh, signed char* __restrict__ wq,
                        float* __restrict__ wsc) {
  const int r = blockIdx.x;          // 0..4095 = (layer,dir,gate-row)
  const int lane = threadIdx.x;      // 64
  float4 v = *(const float4*)(whh + (size_t)r * 256 + lane * 4);
  float m = fmaxf(fmaxf(fabsf(v.x), fabsf(v.y)), fmaxf(fabsf(v.z), fabsf(v.w)));
  #pragma unroll
  for (int off = 32; off > 0; off >>= 1) m = fmaxf(m, __shfl_xor(m, off, 64));
  const float s = fmaxf(m, 1e-20f) * (1.0f / 127.0f);
  const float inv = 1.0f / s;
  int q0 = (int)rintf(v.x * inv), q1 = (int)rintf(v.y * inv);
  int q2 = (int)rintf(v.z * inv), q3 = (int)rintf(v.w * inv);
  u32 pk = (u32)(q0 & 255) | ((u32)(q1 & 255) << 8)
         | ((u32)(q2 & 255) << 16) | ((u32)(q3 & 255) << 24);
  *(u32*)(wq + (size_t)r * 256 + lane * 4) = pk;
  if (lane == 0) wsc[r] = s * (1.0f / 127.0f);
}

// ---------------- bf16 MFMA GEMM: G[m][n] = A[m][:] . W[n][:] + bih[n] + bhh[n] ----------------
__global__ void gemm_k(const u16* __restrict__ A, const u16* __restrict__ W,
                       const float* __restrict__ bih, const float* __restrict__ bhh,
                       u16* __restrict__ G) {
  __shared__ short Asm[64 * 40];
  __shared__ short Bsm[64 * 40];
  const int tid = threadIdx.x;
  const int m0 = blockIdx.x * 64, n0 = blockIdx.y * 64;
  const int wid = tid >> 6, lane = tid & 63;
  const int quad = lane >> 4, lr = lane & 15;
  const int wm = (wid >> 1) * 32, wn = (wid & 1) * 32;
  const int lrow = tid >> 2, lk = (tid & 3) * 8;
  floatx4 acc00 = {0,0,0,0}, acc01 = {0,0,0,0}, acc10 = {0,0,0,0}, acc11 = {0,0,0,0};
  for (int kt = 0; kt < 16; ++kt) {
    const int k0 = kt * 32;
    uint4 av = *(const uint4*)(A + (size_t)(m0 + lrow) * 512 + k0 + lk);
    uint4 bv = *(const uint4*)(W + (size_t)(n0 + lrow) * 512 + k0 + lk);
    __syncthreads();
    *(uint4*)&Asm[lrow * 40 + lk] = av;
    *(uint4*)&Bsm[lrow * 40 + lk] = bv;
    __syncthreads();
    short8v a0 = *(const short8v*)&Asm[(wm + lr) * 40 + quad * 8];
    short8v a1 = *(const short8v*)&Asm[(wm + 16 + lr) * 40 + quad * 8];
    short8v b0 = *(const short8v*)&Bsm[(wn + lr) * 40 + quad * 8];
    short8v b1 = *(const short8v*)&Bsm[(wn + 16 + lr) * 40 + quad * 8];
    acc00 = __builtin_amdgcn_mfma_f32_16x16x32_bf16(a0, b0, acc00, 0, 0, 0);
    acc01 = __builtin_amdgcn_mfma_f32_16x16x32_bf16(a0, b1, acc01, 0, 0, 0);
    acc10 = __builtin_amdgcn_mfma_f32_16x16x32_bf16(a1, b0, acc10, 0, 0, 0);
    acc11 = __builtin_amdgcn_mfma_f32_16x16x32_bf16(a1, b1, acc11, 0, 0, 0);
  }
  #pragma unroll
  for (int j = 0; j < 2; ++j) {
    const int n = n0 + wn + j * 16 + lr;
    const float bias = bih[n] + bhh[n];
    #pragma unroll
    for (int i = 0; i < 2; ++i) {
      const int mb = m0 + wm + i * 16 + quad * 4;
      floatx4 av = (i == 0) ? (j == 0 ? acc00 : acc01) : (j == 0 ? acc10 : acc11);
      #pragma unroll
      for (int rr = 0; rr < 4; ++rr) {
        G[(size_t)(mb + rr) * 2048 + n] = f2bf(av[rr] + bias);
      }
    }
  }
}

// ---------------- LSTM recurrence: block-local, conflict-free, no-drain barrier ----------------
// v9 = v8's block-local i8 design with the three measured serializers removed:
//  (1) SWIZZLED hq: chunk j of batch-row b stored at position j^b. B-frag reads
//      become 8 distinct addresses + broadcast (lanes c and c+8 share an addr)
//      -> 0 bank conflicts (was 16-way, 4.13M conflict-cycles/dispatch).
//  (2) NO SHUFFLES: B-frag is read from row c&7 for ALL 16 cols, so both MFMA
//      sub-tiles compute every batch in every column half. Lane c<8 keeps its
//      sub-0 cells, lane c>=8 keeps sub-1 cells of batch c-8. Even 4 cells per
//      lane, zero ds_bpermute (was 16/step on the same contended LDS pipe).
//  (3) RAW BARRIER: s_waitcnt lgkmcnt(0) + s_barrier (NOT __syncthreads) -> no
//      per-step vmcnt(0) drain, so the 2-deep G prefetch and X-store acks stay
//      in flight across steps instead of serializing into every step.
// Ordering: step st reads hq[par], writes hq[par^1]; st-1's reads of par^1 are
// drained by its own lgkmcnt(0) before its barrier -> one barrier/step is safe.
// Arithmetic is bit-identical to v8 (same quant, same MFMA ops) -> same absmax.
__launch_bounds__(512, 2)
__global__ void rec_k(const u16* __restrict__ G, const signed char* __restrict__ wq_l,
                      const float* __restrict__ wsc_l,
                      u16* __restrict__ Xbf, u32* __restrict__ Xu) {
  __shared__ alignas(16) signed char hq[2][8][256];  // [parity][batch][k], swizzled 16B chunks

  const int tid = threadIdx.x;
  const int dir = blockIdx.x >> 2;
  const int bg = blockIdx.x & 3;
  const int w = tid >> 6;        // wave = hidden chunk w*32
  const int lane = tid & 63;
  const int q = lane >> 4;
  const int c = lane & 15;       // MFMA column
  const int b = c & 7;           // batch in group (both col-halves mirror batches)
  const int sub = c >> 3;        // which 16-row sub-tile this lane's cells use

  const signed char* wq = wq_l + (size_t)dir * 262144;
  const float* wsc = wsc_l + (size_t)dir * 1024;

  // ---- one-time: A-fragments (i8 weights, v8-proven layout) ----
  intx4 A[4][2][4];   // [gate][sub][ktile]
  #pragma unroll
  for (int g = 0; g < 4; ++g)
    #pragma unroll
    for (int s_ = 0; s_ < 2; ++s_) {
      const int row = g * 256 + w * 32 + s_ * 16 + c;
      #pragma unroll
      for (int kt = 0; kt < 4; ++kt)
        A[g][s_][kt] = *(const intx4*)(wq + (size_t)row * 256 + kt * 64 + q * 16);
    }
  // row scales for THIS lane's 4 cells (hidden = w*32 + sub*16 + q*4 + reg)
  float sc[4][4];
  #pragma unroll
  for (int g = 0; g < 4; ++g)
    #pragma unroll
    for (int r = 0; r < 4; ++r)
      sc[g][r] = wsc[g * 256 + w * 32 + sub * 16 + q * 4 + r];

  if (tid < 256) ((uint4*)hq)[tid] = make_uint4(0, 0, 0, 0);  // 4 KB zero
  float cst[4] = {0.f, 0.f, 0.f, 0.f};

  // G for this lane's cells: 4 gates x 4 consecutive hidden, batch b
  const u16* gb_ = G + (size_t)(bg * 8 + b) * 2048 + dir * 1024
                 + w * 32 + sub * 16 + q * 4;
  // 2-deep G prefetch (consumed 2 raw-barriers after issue; never drained early)
  u64 gc[4], gn[4];
  #pragma unroll
  for (int pf = 0; pf < 2; ++pf) {
    const int tn = dir ? (511 - pf) : pf;
    const u16* gp = gb_ + (size_t)tn * 65536;
    u64* dst = pf ? gn : gc;
    dst[0] = *(const u64*)(gp);
    dst[1] = *(const u64*)(gp + 256);
    dst[2] = *(const u64*)(gp + 512);
    dst[3] = *(const u64*)(gp + 768);
  }
  __syncthreads();   // preamble only (full drain once is fine)

  for (int st = 0; st < 512; ++st) {
    const int par = st & 1;
    // B-fragments: batch row b, data chunk j = kt*4+q stored at (j^b)*16.
    // Lanes c and c+8 read the SAME address -> LDS broadcast, conflict-free.
    const signed char* hrow = &hq[par][b][0];
    intx4 bf0 = *(const intx4*)&hrow[((0 * 4 + q) ^ b) * 16];
    intx4 bf1 = *(const intx4*)&hrow[((1 * 4 + q) ^ b) * 16];
    intx4 bf2 = *(const intx4*)&hrow[((2 * 4 + q) ^ b) * 16];
    intx4 bf3 = *(const intx4*)&hrow[((3 * 4 + q) ^ b) * 16];
    // MFMA: acc[g][s_] col c = gate g, sub-tile s_, batch c&7 (duplicated cols)
    intx4 acc[4][2];
    #pragma unroll
    for (int g = 0; g < 4; ++g)
      #pragma unroll
      for (int s_ = 0; s_ < 2; ++s_) {
        intx4 a_ = {0, 0, 0, 0};
        a_ = __builtin_amdgcn_mfma_i32_16x16x64_i8(A[g][s_][0], bf0, a_, 0, 0, 0);
        a_ = __builtin_amdgcn_mfma_i32_16x16x64_i8(A[g][s_][1], bf1, a_, 0, 0, 0);
        a_ = __builtin_amdgcn_mfma_i32_16x16x64_i8(A[g][s_][2], bf2, a_, 0, 0, 0);
        a_ = __builtin_amdgcn_mfma_i32_16x16x64_i8(A[g][s_][3], bf3, a_, 0, 0, 0);
        acc[g][s_] = a_;
      }
    // cell update: 4 cells/lane, even across all 64 lanes, no shuffles
    u16 hb16[4]; float hfv[4];
    #pragma unroll
    for (int reg = 0; reg < 4; ++reg) {
      const float a0v = (float)((c < 8) ? acc[0][0][reg] : acc[0][1][reg]);
      const float a1v = (float)((c < 8) ? acc[1][0][reg] : acc[1][1][reg]);
      const float a2v = (float)((c < 8) ? acc[2][0][reg] : acc[2][1][reg]);
      const float a3v = (float)((c < 8) ? acc[3][0][reg] : acc[3][1][reg]);
      const float si = bf2f((u16)(gc[0] >> (16 * reg))) + a0v * sc[0][reg];
      const float sf = bf2f((u16)(gc[1] >> (16 * reg))) + a1v * sc[1][reg];
      const float sg = bf2f((u16)(gc[2] >> (16 * reg))) + a2v * sc[2][reg];
      const float so = bf2f((u16)(gc[3] >> (16 * reg))) + a3v * sc[3][reg];
      const float ig = sigf(si), fg = sigf(sf), gg = tanh_f(sg), og = sigf(so);
      const float cn = fg * cst[reg] + ig * gg;
      const float hn = og * tanh_f(cn);
      cst[reg] = cn;
      hfv[reg] = hn;
      hb16[reg] = f2bf(hn);
    }
    // quantize h -> i8, one swizzled u32 write (2-way banks = free, bijective)
    {
      const int q0 = (int)rintf(hfv[0] * 127.f);
      const int q1 = (int)rintf(hfv[1] * 127.f);
      const int q2 = (int)rintf(hfv[2] * 127.f);
      const int q3 = (int)rintf(hfv[3] * 127.f);
      const u32 qpk = (u32)(q0 & 255) | ((u32)(q1 & 255) << 8)
                    | ((u32)(q2 & 255) << 16) | ((u32)(q3 & 255) << 24);
      const int chunk = 2 * w + sub;             // 16B data-chunk index
      *(u32*)&hq[par ^ 1][b][((chunk ^ b) * 16) + q * 4] = qpk;
    }
    // X output: direct global write (floats across the raw barrier freely)
    {
      const int tt = dir ? (511 - st) : st;
      const size_t xo = ((size_t)tt * 32 + bg * 8 + b) * 512 + dir * 256
                      + w * 32 + sub * 16 + q * 4;
      if (Xbf) {
        u64 xv = (u64)hb16[0] | ((u64)hb16[1] << 16)
               | ((u64)hb16[2] << 32) | ((u64)hb16[3] << 48);
        *(u64*)(Xbf + xo) = xv;
      } else {
        uint4 xv;
        xv.x = ((u32)hb16[0] << 16) | f2bf(hfv[0] - bf2f(hb16[0]));
        xv.y = ((u32)hb16[1] << 16) | f2bf(hfv[1] - bf2f(hb16[1]));
        xv.z = ((u32)hb16[2] << 16) | f2bf(hfv[2] - bf2f(hb16[2]));
        xv.w = ((u32)hb16[3] << 16) | f2bf(hfv[3] - bf2f(hb16[3]));
        *(uint4*)(Xu + xo) = xv;
      }
    }
    // rotate G pipeline: consume st (gc), promote gn, issue st+2
    gc[0] = gn[0]; gc[1] = gn[1]; gc[2] = gn[2]; gc[3] = gn[3];
    {
      const int stn = (st + 2 < 512) ? st + 2 : 511;
      const int tn = dir ? (511 - stn) : stn;
      const u16* gp = gb_ + (size_t)tn * 65536;
      gn[0] = *(const u64*)(gp);
      gn[1] = *(const u64*)(gp + 256);
      gn[2] = *(const u64*)(gp + 512);
      gn[3] = *(const u64*)(gp + 768);
    }
    // raw barrier: LDS-drain only, NO vmcnt drain (G/X stay in flight)
    asm volatile("s_waitcnt lgkmcnt(0)" ::: "memory");
    __builtin_amdgcn_s_barrier();
    __builtin_amdgcn_sched_barrier(0);
  }
}

// ---------------- LayerNorm + classifier head; logits -> d_out+1 ----------------
// X2u: packed (bf16hi<<16|bf16lo) per element; decode = bf2f(hi)+bf2f(lo)
__global__ void head_k(const u32* __restrict__ X2u, const float* __restrict__ gamma,
                       const float* __restrict__ beta, const float* __restrict__ cw,
                       const float* __restrict__ cb, float* __restrict__ out) {
  __shared__ float red[9][64];
  const int m = blockIdx.x, lane = threadIdx.x;
  const int s = m >> 5, b = m & 31;
  const uint4* xp = (const uint4*)(X2u + (size_t)m * 512) + lane * 2;
  uint4 a0 = xp[0], a1 = xp[1];
  float x[8];
  x[0] = decode_hl(a0.x); x[1] = decode_hl(a0.y);
  x[2] = decode_hl(a0.z); x[3] = decode_hl(a0.w);
  x[4] = decode_hl(a1.x); x[5] = decode_hl(a1.y);
  x[6] = decode_hl(a1.z); x[7] = decode_hl(a1.w);
  float sm = 0.f, sq = 0.f;
  #pragma unroll
  for (int i = 0; i < 8; ++i) { sm += x[i]; sq += x[i] * x[i]; }
  #pragma unroll
  for (int off = 32; off > 0; off >>= 1) {
    sm += __shfl_xor(sm, off, 64);
    sq += __shfl_xor(sq, off, 64);
  }
  const float mu = sm * (1.0f / 512.0f);
  const float var = sq * (1.0f / 512.0f) - mu * mu;
  const float rs = rsqrtf(var + 1e-5f);
  const float4* gp = (const float4*)gamma + lane * 2;
  const float4* bp = (const float4*)beta + lane * 2;
  float4 g0 = gp[0], g1 = gp[1], be0 = bp[0], be1 = bp[1];
  float nv[8];
  nv[0] = (x[0] - mu) * rs * g0.x + be0.x;
  nv[1] = (x[1] - mu) * rs * g0.y + be0.y;
  nv[2] = (x[2] - mu) * rs * g0.z + be0.z;
  nv[3] = (x[3] - mu) * rs * g0.w + be0.w;
  nv[4] = (x[4] - mu) * rs * g1.x + be1.x;
  nv[5] = (x[5] - mu) * rs * g1.y + be1.y;
  nv[6] = (x[6] - mu) * rs * g1.z + be1.z;
  nv[7] = (x[7] - mu) * rs * g1.w + be1.w;
  #pragma unroll
  for (int c = 0; c < 9; ++c) {
    const float4* wp = (const float4*)(cw + (size_t)c * 512) + lane * 2;
    float4 w0 = wp[0], w1 = wp[1];
    red[c][lane] = nv[0]*w0.x + nv[1]*w0.y + nv[2]*w0.z + nv[3]*w0.w
                 + nv[4]*w1.x + nv[5]*w1.y + nv[6]*w1.z + nv[7]*w1.w;
  }
  __syncthreads();
  if (lane < 9) {
    float t = 0.f;
    for (int i = 0; i < 64; ++i) t += red[lane][i];
    out[1 + ((size_t)b * 512 + s) * 9 + lane] = t + cb[lane];
  }
}

// ---------------- CRF NLL: one wave per batch element ----------------
__global__ void crf_k(const float* __restrict__ logits, const int* __restrict__ labels,
                      const int* __restrict__ lens, const float* __restrict__ tr,
                      float* __restrict__ loss) {
  const int b = blockIdx.x, lane = threadIdx.x;
  const int len = lens[b];
  float trj[9];
  #pragma unroll
  for (int i = 0; i < 9; ++i) trj[i] = 0.f;
  if (lane < 9) {
    #pragma unroll
    for (int i = 0; i < 9; ++i) trj[i] = tr[i * 11 + lane];
  }
  float alpha = -1e30f;
  if (lane < 9) alpha = tr[9 * 11 + lane] + logits[(size_t)b * 512 * 9 + lane];
  for (int t = 1; t < len; ++t) {
    float e = (lane < 9) ? logits[((size_t)b * 512 + t) * 9 + lane] : 0.f;
    float v[9];
    float mx = -1e30f;
    #pragma unroll
    for (int i = 0; i < 9; ++i) {
      v[i] = __shfl(alpha, i, 64) + trj[i];
      mx = fmaxf(mx, v[i]);
    }
    float ss = 0.f;
    #pragma unroll
    for (int i = 0; i < 9; ++i) ss += __expf(v[i] - mx);
    float na = mx + __logf(ss) + e;
    if (lane < 9) alpha = na;
  }
  float fin = (lane < 9) ? alpha + tr[lane * 11 + 10] : -1e30f;
  float mx = fin;
  #pragma unroll
  for (int off = 8; off > 0; off >>= 1) mx = fmaxf(mx, __shfl_xor(mx, off, 64));
  float es = (lane < 9) ? __expf(fin - mx) : 0.f;
  #pragma unroll
  for (int off = 8; off > 0; off >>= 1) es += __shfl_xor(es, off, 64);
  const float logZ = mx + __logf(es);
  float emit = 0.f, ts = 0.f;
  for (int t = lane; t < len; t += 64) {
    int y = labels[b * 512 + t];
    emit += logits[((size_t)b * 512 + t) * 9 + y];
  }
  for (int t = 1 + lane; t < len; t += 64) {
    int y0 = labels[b * 512 + t - 1], y1 = labels[b * 512 + t];
    ts += tr[y0 * 11 + y1];
  }
  #pragma unroll
  for (int off = 32; off > 0; off >>= 1) {
    emit += __shfl_xor(emit, off, 64);
    ts += __shfl_xor(ts, off, 64);
  }
  if (lane == 0) {
    int y0 = labels[b * 512], yl = labels[b * 512 + len - 1];
    float gold = emit + ts + tr[9 * 11 + y0] + tr[yl * 11 + 10];
    atomicAdd(loss, (logZ - gold) * (1.0f / 32.0f));
  }
}

extern "C" void kernel_launch(void* const* d_in, const int* in_sizes, int n_in,
                              void* d_out, int out_size, void* d_ws, size_t ws_size,
                              hipStream_t stream) {
  const int* ids = (const int*)d_in[0];
  const int* amask = (const int*)d_in[1];
  const int* lens = (const int*)d_in[2];
  const int* labels = (const int*)d_in[3];
  const float* emb = (const float*)d_in[4];
  const float* w_ih = (const float*)d_in[5];
  const float* w_hh = (const float*)d_in[6];
  const float* b_ih = (const float*)d_in[7];
  const float* b_hh = (const float*)d_in[8];
  const float* gamma = (const float*)d_in[9];
  const float* beta = (const float*)d_in[10];
  const float* cw = (const float*)d_in[11];
  const float* cb = (const float*)d_in[12];
  const float* tr = (const float*)d_in[13];
  (void)in_sizes; (void)n_in; (void)out_size;

  if (ws_size < WS_NEEDED) return;  // workspace too small -> clean failure

  char* p = (char*)d_ws;
  u16* X0 = (u16*)p;      p += (size_t)16384 * 512 * 2;        // 16.78 MB
  u16* Wbf = (u16*)p;     p += (size_t)2 * 2 * 1024 * 512 * 2; // 4.19 MB
  u16* G = (u16*)p;       p += (size_t)16384 * 2048 * 2;       // 67.1 MB
  u16* X1 = (u16*)p;      p += (size_t)16384 * 512 * 2;        // 16.78 MB
  u32* X2u = (u32*)p;     p += (size_t)16384 * 512 * 4;        // 33.55 MB
  float* out = (float*)d_out;

  // i8 Whh + per-row scales live in the X0 region's head, written AFTER gemm0
  // consumes X0 (X0 is dead from then on; gemm1 reads X1, rec1 writes X2u).
  signed char* Wq = (signed char*)X0;             // 4096 x 256 = 1 MB
  float* Wsc = (float*)((char*)X0 + 1048576);     // 4096 floats = 16 KB

  prep_k<<<16384, 64, 0, stream>>>(ids, amask, emb, X0);
  conv_k<<<1024, 256, 0, stream>>>(w_ih, Wbf, 262144);
  zero_k<<<1, 64, 0, stream>>>(out);
  // Layer 0
  gemm_k<<<dim3(256, 32), 256, 0, stream>>>(X0, Wbf, b_ih, b_hh, G);
  convw_k<<<4096, 64, 0, stream>>>(w_hh, Wq, Wsc);   // X0 dead after gemm0
  rec_k<<<8, 512, 0, stream>>>(G, Wq, Wsc, X1, nullptr);
  // Layer 1
  gemm_k<<<dim3(256, 32), 256, 0, stream>>>(X1, Wbf + 2 * 1024 * 512,
                                            b_ih + 2048, b_hh + 2048, G);
  rec_k<<<8, 512, 0, stream>>>(G, Wq + 2 * 262144, Wsc + 2048, nullptr, X2u);
  // Head + CRF
  head_k<<<16384, 64, 0, stream>>>(X2u, gamma, beta, cw, cb, out);
  crf_k<<<32, 64, 0, stream>>>(out + 1, labels, lens, tr, out);
}

// Round 10
// 1503.219 us; speedup vs baseline: 1.8910x; 1.6699x over previous
//
#include <hip/hip_runtime.h>

// Problem dims
#define B_ 32
#define S_ 512
#define D_ 512
#define H_ 256

typedef float floatx4 __attribute__((ext_vector_type(4)));
typedef short short8v __attribute__((ext_vector_type(8)));
typedef int intx4 __attribute__((ext_vector_type(4)));
typedef unsigned short u16;
typedef unsigned int u32;
typedef unsigned long long u64;

#define WS_NEEDED 138575872ull

__device__ __forceinline__ u16 f2bf(float f) {
  u32 x = __float_as_uint(f);
  x += 0x7fffu + ((x >> 16) & 1u);   // RNE
  return (u16)(x >> 16);
}
__device__ __forceinline__ float bf2f(u16 h) {
  return __uint_as_float(((u32)h) << 16);
}
__device__ __forceinline__ float decode_hl(u32 v) {
  return bf2f((u16)(v >> 16)) + bf2f((u16)(v & 0xffffu));
}
__device__ __forceinline__ float sigf(float x) {
  return 1.0f / (1.0f + __expf(-x));
}
__device__ __forceinline__ float tanh_f(float x) {
  float e = __expf(-2.0f * fabsf(x));
  float r = (1.0f - e) / (1.0f + e);
  return copysignf(r, x);
}
// fast reciprocal: single v_rcp_f32 (~1 ulp) instead of the ~11-op IEEE div
// expansion. Error ~1e-7 relative — invisible under the i8-quant noise.
__device__ __forceinline__ float rcp_f(float x) {
  float r; asm("v_rcp_f32 %0, %1" : "=v"(r) : "v"(x)); return r;
}
__device__ __forceinline__ float sig_fast(float x) {
  return rcp_f(1.0f + __expf(-x));
}
__device__ __forceinline__ float tanh_fast(float x) {
  float e = __expf(-2.0f * fabsf(x));
  float r = (1.0f - e) * rcp_f(1.0f + e);
  return copysignf(r, x);
}

struct alignas(16) U16x8 { u16 v[8]; };

// ---------------- embedding -> X0 bf16, time-major (m = s*32+b, 512 feats) ----------------
__global__ void prep_k(const int* __restrict__ ids, const int* __restrict__ amask,
                       const float* __restrict__ emb, u16* __restrict__ X0) {
  int m = blockIdx.x;            // m = s*32 + b
  int lane = threadIdx.x;        // 64
  int s = m >> 5, b = m & 31;
  int id = ids[b * S_ + s];
  int mk = amask[b * S_ + s];
  const float4* src = (const float4*)(emb + (size_t)id * D_) + lane * 2;
  float4 v0 = src[0], v1 = src[1];
  if (!mk) { v0 = make_float4(0,0,0,0); v1 = make_float4(0,0,0,0); }
  U16x8 o;
  o.v[0]=f2bf(v0.x); o.v[1]=f2bf(v0.y); o.v[2]=f2bf(v0.z); o.v[3]=f2bf(v0.w);
  o.v[4]=f2bf(v1.x); o.v[5]=f2bf(v1.y); o.v[6]=f2bf(v1.z); o.v[7]=f2bf(v1.w);
  *(U16x8*)(X0 + (size_t)m * D_ + lane * 8) = o;
}

// ---------------- fp32 -> bf16 weight convert (w_ih, 2*2*1024*512 elems) ----------------
__global__ void conv_k(const float* __restrict__ w, u16* __restrict__ wbf, int n8) {
  int idx = blockIdx.x * blockDim.x + threadIdx.x;
  if (idx >= n8) return;
  const float4* s = (const float4*)w + (size_t)idx * 2;
  float4 v0 = s[0], v1 = s[1];
  U16x8 o;
  o.v[0]=f2bf(v0.x); o.v[1]=f2bf(v0.y); o.v[2]=f2bf(v0.z); o.v[3]=f2bf(v0.w);
  o.v[4]=f2bf(v1.x); o.v[5]=f2bf(v1.y); o.v[6]=f2bf(v1.z); o.v[7]=f2bf(v1.w);
  *(U16x8*)(wbf + (size_t)idx * 8) = o;
}

// ---------------- zero loss ----------------
__global__ void zero_k(float* __restrict__ loss) {
  if (threadIdx.x == 0) *loss = 0.f;
}

// ---------------- w_hh fp32 -> per-row-scaled i8 (4096 rows of 256) ----------------
// w = s_row*q, q=rint(w/s_row) in [-127,127]; wsc[r] = s_row/127 (h's 1/127 folded in):
// gate_rec = sum(w*h) ~ wsc[r] * sum(qw*qh) with qh = rint(h*127).
__global__ void convw_k(const float* __restrict__ whh, signed char* __restrict__ wq,
                        float* __restrict__ wsc) {
  const int r = blockIdx.x;          // 0..4095 = (layer,dir,gate-row)
  const int lane = threadIdx.x;      // 64
  float4 v = *(const float4*)(whh + (size_t)r * 256 + lane * 4);
  float m = fmaxf(fmaxf(fabsf(v.x), fabsf(v.y)), fmaxf(fabsf(v.z), fabsf(v.w)));
  #pragma unroll
  for (int off = 32; off > 0; off >>= 1) m = fmaxf(m, __shfl_xor(m, off, 64));
  const float s = fmaxf(m, 1e-20f) * (1.0f / 127.0f);
  const float inv = 1.0f / s;
  int q0 = (int)rintf(v.x * inv), q1 = (int)rintf(v.y * inv);
  int q2 = (int)rintf(v.z * inv), q3 = (int)rintf(v.w * inv);
  u32 pk = (u32)(q0 & 255) | ((u32)(q1 & 255) << 8)
         | ((u32)(q2 & 255) << 16) | ((u32)(q3 & 255) << 24);
  *(u32*)(wq + (size_t)r * 256 + lane * 4) = pk;
  if (lane == 0) wsc[r] = s * (1.0f / 127.0f);
}

// ---------------- bf16 MFMA GEMM: G[m][n] = A[m][:] . W[n][:] + bih[n] + bhh[n] ----------------
__global__ void gemm_k(const u16* __restrict__ A, const u16* __restrict__ W,
                       const float* __restrict__ bih, const float* __restrict__ bhh,
                       u16* __restrict__ G) {
  __shared__ short Asm[64 * 40];
  __shared__ short Bsm[64 * 40];
  const int tid = threadIdx.x;
  const int m0 = blockIdx.x * 64, n0 = blockIdx.y * 64;
  const int wid = tid >> 6, lane = tid & 63;
  const int quad = lane >> 4, lr = lane & 15;
  const int wm = (wid >> 1) * 32, wn = (wid & 1) * 32;
  const int lrow = tid >> 2, lk = (tid & 3) * 8;
  floatx4 acc00 = {0,0,0,0}, acc01 = {0,0,0,0}, acc10 = {0,0,0,0}, acc11 = {0,0,0,0};
  for (int kt = 0; kt < 16; ++kt) {
    const int k0 = kt * 32;
    uint4 av = *(const uint4*)(A + (size_t)(m0 + lrow) * 512 + k0 + lk);
    uint4 bv = *(const uint4*)(W + (size_t)(n0 + lrow) * 512 + k0 + lk);
    __syncthreads();
    *(uint4*)&Asm[lrow * 40 + lk] = av;
    *(uint4*)&Bsm[lrow * 40 + lk] = bv;
    __syncthreads();
    short8v a0 = *(const short8v*)&Asm[(wm + lr) * 40 + quad * 8];
    short8v a1 = *(const short8v*)&Asm[(wm + 16 + lr) * 40 + quad * 8];
    short8v b0 = *(const short8v*)&Bsm[(wn + lr) * 40 + quad * 8];
    short8v b1 = *(const short8v*)&Bsm[(wn + 16 + lr) * 40 + quad * 8];
    acc00 = __builtin_amdgcn_mfma_f32_16x16x32_bf16(a0, b0, acc00, 0, 0, 0);
    acc01 = __builtin_amdgcn_mfma_f32_16x16x32_bf16(a0, b1, acc01, 0, 0, 0);
    acc10 = __builtin_amdgcn_mfma_f32_16x16x32_bf16(a1, b0, acc10, 0, 0, 0);
    acc11 = __builtin_amdgcn_mfma_f32_16x16x32_bf16(a1, b1, acc11, 0, 0, 0);
  }
  #pragma unroll
  for (int j = 0; j < 2; ++j) {
    const int n = n0 + wn + j * 16 + lr;
    const float bias = bih[n] + bhh[n];
    #pragma unroll
    for (int i = 0; i < 2; ++i) {
      const int mb = m0 + wm + i * 16 + quad * 4;
      floatx4 av = (i == 0) ? (j == 0 ? acc00 : acc01) : (j == 0 ? acc10 : acc11);
      #pragma unroll
      for (int rr = 0; rr < 4; ++rr) {
        G[(size_t)(mb + rr) * 2048 + n] = f2bf(av[rr] + bias);
      }
    }
  }
}

// ---------------- LSTM recurrence: block-local, 16 blocks, matrix/VALU balanced ----------------
// v10 = v9 with the two measured pipe loads shrunk:
//  (1) 16 BLOCKS x 4 BATCHES (was 8 x 8). Matrix-pipe time per block-step is
//      invariant to batch count (each block streams the full Whh: 64 MFMA/SIMD
//      x ~20cy = ~1300cy), so 2x more CUs keeps MFMA constant while QUARTERING
//      per-lane cell count to 2 -> VALU (~78% busy in v9, the larger pipe)
//      drops below the matrix floor.
//      Col map: c -> batch c&3, sub s=(c>>2)&1, regs {r0,r0+1}, r0=((c>>3)&1)*2
//      (bijective, no shuffles, all acc indices compile-time).
//  (2) FAST RCP: v_rcp_f32 for sigmoid/tanh denominators. Without fast-math
//      each 1/(1+e) expanded to the ~11-op IEEE div sequence (~20 divs/lane/
//      step = ~900cy/SIMD). 1-ulp error, invisible under i8-quant noise.
// Everything else (swizzled hq, raw lgkm-only barrier, 2-deep G prefetch,
// direct X store) = v9.
__launch_bounds__(512, 2)
__global__ void rec_k(const u16* __restrict__ G, const signed char* __restrict__ wq_l,
                      const float* __restrict__ wsc_l,
                      u16* __restrict__ Xbf, u32* __restrict__ Xu) {
  __shared__ alignas(16) signed char hq[2][4][256];  // [parity][batch][k], swizzled 16B chunks

  const int tid = threadIdx.x;
  const int dir = blockIdx.x >> 3;
  const int bg = blockIdx.x & 7;   // 8 groups x 4 batches
  const int w = tid >> 6;          // wave = hidden chunk w*32
  const int lane = tid & 63;
  const int q = lane >> 4;
  const int c = lane & 15;         // MFMA column
  const int b4 = c & 3;            // batch in group (cols duplicate batches 4x)
  const int s = (c >> 2) & 1;      // sub-tile for this lane's cells
  const int r0 = ((c >> 3) & 1) * 2;  // first reg of this lane's 2 cells

  const signed char* wq = wq_l + (size_t)dir * 262144;
  const float* wsc = wsc_l + (size_t)dir * 1024;

  // ---- one-time: A-fragments (i8 weights, v8-proven layout) ----
  intx4 A[4][2][4];   // [gate][sub][ktile]
  #pragma unroll
  for (int g = 0; g < 4; ++g)
    #pragma unroll
    for (int s_ = 0; s_ < 2; ++s_) {
      const int row = g * 256 + w * 32 + s_ * 16 + c;
      #pragma unroll
      for (int kt = 0; kt < 4; ++kt)
        A[g][s_][kt] = *(const intx4*)(wq + (size_t)row * 256 + kt * 64 + q * 16);
    }
  // row scales for THIS lane's 2 cells (hidden = w*32 + s*16 + q*4 + r0 + k)
  float sc[4][2];
  #pragma unroll
  for (int g = 0; g < 4; ++g)
    #pragma unroll
    for (int k = 0; k < 2; ++k)
      sc[g][k] = wsc[g * 256 + w * 32 + s * 16 + q * 4 + r0 + k];

  if (tid < 128) ((uint4*)hq)[tid] = make_uint4(0, 0, 0, 0);  // 2 KB zero
  float cst[2] = {0.f, 0.f};

  // G for this lane's cells: 4 gates x 2 consecutive hidden, batch b4
  const u16* gb_ = G + (size_t)(bg * 4 + b4) * 2048 + dir * 1024
                 + w * 32 + s * 16 + q * 4 + r0;
  // 2-deep G prefetch (consumed 2 raw-barriers after issue; never drained early)
  u32 gc[4], gn[4];
  #pragma unroll
  for (int pf = 0; pf < 2; ++pf) {
    const int tn = dir ? (511 - pf) : pf;
    const u16* gp = gb_ + (size_t)tn * 65536;
    u32* dst = pf ? gn : gc;
    dst[0] = *(const u32*)(gp);
    dst[1] = *(const u32*)(gp + 256);
    dst[2] = *(const u32*)(gp + 512);
    dst[3] = *(const u32*)(gp + 768);
  }
  __syncthreads();   // preamble only (full drain once is fine)

  for (int st = 0; st < 512; ++st) {
    const int par = st & 1;
    // B-fragments: batch row b4, data chunk j = kt*4+q stored at (j^b4)*16.
    // 4 lanes per address -> LDS broadcast; distinct addrs spread by XOR.
    const signed char* hrow = &hq[par][b4][0];
    intx4 bf0 = *(const intx4*)&hrow[((0 * 4 + q) ^ b4) * 16];
    intx4 bf1 = *(const intx4*)&hrow[((1 * 4 + q) ^ b4) * 16];
    intx4 bf2 = *(const intx4*)&hrow[((2 * 4 + q) ^ b4) * 16];
    intx4 bf3 = *(const intx4*)&hrow[((3 * 4 + q) ^ b4) * 16];
    // MFMA: acc[g][s_] col c = gate g, sub-tile s_, batch c&3 (duplicated cols)
    intx4 acc[4][2];
    #pragma unroll
    for (int g = 0; g < 4; ++g)
      #pragma unroll
      for (int s_ = 0; s_ < 2; ++s_) {
        intx4 a_ = {0, 0, 0, 0};
        a_ = __builtin_amdgcn_mfma_i32_16x16x64_i8(A[g][s_][0], bf0, a_, 0, 0, 0);
        a_ = __builtin_amdgcn_mfma_i32_16x16x64_i8(A[g][s_][1], bf1, a_, 0, 0, 0);
        a_ = __builtin_amdgcn_mfma_i32_16x16x64_i8(A[g][s_][2], bf2, a_, 0, 0, 0);
        a_ = __builtin_amdgcn_mfma_i32_16x16x64_i8(A[g][s_][3], bf3, a_, 0, 0, 0);
        acc[g][s_] = a_;
      }
    // select this lane's sub-tile (compile-time element indices only)
    intx4 x0 = s ? acc[0][1] : acc[0][0];
    intx4 x1 = s ? acc[1][1] : acc[1][0];
    intx4 x2 = s ? acc[2][1] : acc[2][0];
    intx4 x3 = s ? acc[3][1] : acc[3][0];
    // cell update: 2 cells/lane, fast-rcp transcendentals
    u16 hb16[2]; float hfv[2];
    #pragma unroll
    for (int k = 0; k < 2; ++k) {
      const float a0v = (float)(r0 ? x0[2 + k] : x0[k]);
      const float a1v = (float)(r0 ? x1[2 + k] : x1[k]);
      const float a2v = (float)(r0 ? x2[2 + k] : x2[k]);
      const float a3v = (float)(r0 ? x3[2 + k] : x3[k]);
      const float si = bf2f((u16)(gc[0] >> (16 * k))) + a0v * sc[0][k];
      const float sf = bf2f((u16)(gc[1] >> (16 * k))) + a1v * sc[1][k];
      const float sg = bf2f((u16)(gc[2] >> (16 * k))) + a2v * sc[2][k];
      const float so = bf2f((u16)(gc[3] >> (16 * k))) + a3v * sc[3][k];
      const float ig = sig_fast(si), fg = sig_fast(sf);
      const float gg = tanh_fast(sg), og = sig_fast(so);
      const float cn = fg * cst[k] + ig * gg;
      const float hn = og * tanh_fast(cn);
      cst[k] = cn;
      hfv[k] = hn;
      hb16[k] = f2bf(hn);
    }
    // quantize h -> i8, one swizzled u16 write (sub-dword byte-enables; 2-way ok)
    {
      const int q0v = (int)rintf(hfv[0] * 127.f);
      const int q1v = (int)rintf(hfv[1] * 127.f);
      const u16 pk = (u16)((q0v & 255) | ((q1v & 255) << 8));
      const int chunk = 2 * w + s;             // 16B data-chunk index
      *(u16*)((signed char*)hq + (size_t)(par ^ 1) * 1024 + b4 * 256
              + ((chunk ^ b4) * 16) + q * 4 + r0) = pk;
    }
    // X output: direct global write (floats across the raw barrier freely)
    {
      const int tt = dir ? (511 - st) : st;
      const size_t xo = ((size_t)tt * 32 + bg * 4 + b4) * 512 + dir * 256
                      + w * 32 + s * 16 + q * 4 + r0;
      if (Xbf) {
        *(u32*)(Xbf + xo) = (u32)hb16[0] | ((u32)hb16[1] << 16);
      } else {
        u32 xa = ((u32)hb16[0] << 16) | f2bf(hfv[0] - bf2f(hb16[0]));
        u32 xb = ((u32)hb16[1] << 16) | f2bf(hfv[1] - bf2f(hb16[1]));
        *(u64*)(Xu + xo) = (u64)xa | ((u64)xb << 32);
      }
    }
    // rotate G pipeline: consume st (gc), promote gn, issue st+2
    gc[0] = gn[0]; gc[1] = gn[1]; gc[2] = gn[2]; gc[3] = gn[3];
    {
      const int stn = (st + 2 < 512) ? st + 2 : 511;
      const int tn = dir ? (511 - stn) : stn;
      const u16* gp = gb_ + (size_t)tn * 65536;
      gn[0] = *(const u32*)(gp);
      gn[1] = *(const u32*)(gp + 256);
      gn[2] = *(const u32*)(gp + 512);
      gn[3] = *(const u32*)(gp + 768);
    }
    // raw barrier: LDS-drain only, NO vmcnt drain (G/X stay in flight)
    asm volatile("s_waitcnt lgkmcnt(0)" ::: "memory");
    __builtin_amdgcn_s_barrier();
    __builtin_amdgcn_sched_barrier(0);
  }
}

// ---------------- LayerNorm + classifier head; logits -> d_out+1 ----------------
// X2u: packed (bf16hi<<16|bf16lo) per element; decode = bf2f(hi)+bf2f(lo)
__global__ void head_k(const u32* __restrict__ X2u, const float* __restrict__ gamma,
                       const float* __restrict__ beta, const float* __restrict__ cw,
                       const float* __restrict__ cb, float* __restrict__ out) {
  __shared__ float red[9][64];
  const int m = blockIdx.x, lane = threadIdx.x;
  const int s = m >> 5, b = m & 31;
  const uint4* xp = (const uint4*)(X2u + (size_t)m * 512) + lane * 2;
  uint4 a0 = xp[0], a1 = xp[1];
  float x[8];
  x[0] = decode_hl(a0.x); x[1] = decode_hl(a0.y);
  x[2] = decode_hl(a0.z); x[3] = decode_hl(a0.w);
  x[4] = decode_hl(a1.x); x[5] = decode_hl(a1.y);
  x[6] = decode_hl(a1.z); x[7] = decode_hl(a1.w);
  float sm = 0.f, sq = 0.f;
  #pragma unroll
  for (int i = 0; i < 8; ++i) { sm += x[i]; sq += x[i] * x[i]; }
  #pragma unroll
  for (int off = 32; off > 0; off >>= 1) {
    sm += __shfl_xor(sm, off, 64);
    sq += __shfl_xor(sq, off, 64);
  }
  const float mu = sm * (1.0f / 512.0f);
  const float var = sq * (1.0f / 512.0f) - mu * mu;
  const float rs = rsqrtf(var + 1e-5f);
  const float4* gp = (const float4*)gamma + lane * 2;
  const float4* bp = (const float4*)beta + lane * 2;
  float4 g0 = gp[0], g1 = gp[1], be0 = bp[0], be1 = bp[1];
  float nv[8];
  nv[0] = (x[0] - mu) * rs * g0.x + be0.x;
  nv[1] = (x[1] - mu) * rs * g0.y + be0.y;
  nv[2] = (x[2] - mu) * rs * g0.z + be0.z;
  nv[3] = (x[3] - mu) * rs * g0.w + be0.w;
  nv[4] = (x[4] - mu) * rs * g1.x + be1.x;
  nv[5] = (x[5] - mu) * rs * g1.y + be1.y;
  nv[6] = (x[6] - mu) * rs * g1.z + be1.z;
  nv[7] = (x[7] - mu) * rs * g1.w + be1.w;
  #pragma unroll
  for (int c = 0; c < 9; ++c) {
    const float4* wp = (const float4*)(cw + (size_t)c * 512) + lane * 2;
    float4 w0 = wp[0], w1 = wp[1];
    red[c][lane] = nv[0]*w0.x + nv[1]*w0.y + nv[2]*w0.z + nv[3]*w0.w
                 + nv[4]*w1.x + nv[5]*w1.y + nv[6]*w1.z + nv[7]*w1.w;
  }
  __syncthreads();
  if (lane < 9) {
    float t = 0.f;
    for (int i = 0; i < 64; ++i) t += red[lane][i];
    out[1 + ((size_t)b * 512 + s) * 9 + lane] = t + cb[lane];
  }
}

// ---------------- CRF NLL: one wave per batch element ----------------
__global__ void crf_k(const float* __restrict__ logits, const int* __restrict__ labels,
                      const int* __restrict__ lens, const float* __restrict__ tr,
                      float* __restrict__ loss) {
  const int b = blockIdx.x, lane = threadIdx.x;
  const int len = lens[b];
  float trj[9];
  #pragma unroll
  for (int i = 0; i < 9; ++i) trj[i] = 0.f;
  if (lane < 9) {
    #pragma unroll
    for (int i = 0; i < 9; ++i) trj[i] = tr[i * 11 + lane];
  }
  float alpha = -1e30f;
  if (lane < 9) alpha = tr[9 * 11 + lane] + logits[(size_t)b * 512 * 9 + lane];
  for (int t = 1; t < len; ++t) {
    float e = (lane < 9) ? logits[((size_t)b * 512 + t) * 9 + lane] : 0.f;
    float v[9];
    float mx = -1e30f;
    #pragma unroll
    for (int i = 0; i < 9; ++i) {
      v[i] = __shfl(alpha, i, 64) + trj[i];
      mx = fmaxf(mx, v[i]);
    }
    float ss = 0.f;
    #pragma unroll
    for (int i = 0; i < 9; ++i) ss += __expf(v[i] - mx);
    float na = mx + __logf(ss) + e;
    if (lane < 9) alpha = na;
  }
  float fin = (lane < 9) ? alpha + tr[lane * 11 + 10] : -1e30f;
  float mx = fin;
  #pragma unroll
  for (int off = 8; off > 0; off >>= 1) mx = fmaxf(mx, __shfl_xor(mx, off, 64));
  float es = (lane < 9) ? __expf(fin - mx) : 0.f;
  #pragma unroll
  for (int off = 8; off > 0; off >>= 1) es += __shfl_xor(es, off, 64);
  const float logZ = mx + __logf(es);
  float emit = 0.f, ts = 0.f;
  for (int t = lane; t < len; t += 64) {
    int y = labels[b * 512 + t];
    emit += logits[((size_t)b * 512 + t) * 9 + y];
  }
  for (int t = 1 + lane; t < len; t += 64) {
    int y0 = labels[b * 512 + t - 1], y1 = labels[b * 512 + t];
    ts += tr[y0 * 11 + y1];
  }
  #pragma unroll
  for (int off = 32; off > 0; off >>= 1) {
    emit += __shfl_xor(emit, off, 64);
    ts += __shfl_xor(ts, off, 64);
  }
  if (lane == 0) {
    int y0 = labels[b * 512], yl = labels[b * 512 + len - 1];
    float gold = emit + ts + tr[9 * 11 + y0] + tr[yl * 11 + 10];
    atomicAdd(loss, (logZ - gold) * (1.0f / 32.0f));
  }
}

extern "C" void kernel_launch(void* const* d_in, const int* in_sizes, int n_in,
                              void* d_out, int out_size, void* d_ws, size_t ws_size,
                              hipStream_t stream) {
  const int* ids = (const int*)d_in[0];
  const int* amask = (const int*)d_in[1];
  const int* lens = (const int*)d_in[2];
  const int* labels = (const int*)d_in[3];
  const float* emb = (const float*)d_in[4];
  const float* w_ih = (const float*)d_in[5];
  const float* w_hh = (const float*)d_in[6];
  const float* b_ih = (const float*)d_in[7];
  const float* b_hh = (const float*)d_in[8];
  const float* gamma = (const float*)d_in[9];
  const float* beta = (const float*)d_in[10];
  const float* cw = (const float*)d_in[11];
  const float* cb = (const float*)d_in[12];
  const float* tr = (const float*)d_in[13];
  (void)in_sizes; (void)n_in; (void)out_size;

  if (ws_size < WS_NEEDED) return;  // workspace too small -> clean failure

  char* p = (char*)d_ws;
  u16* X0 = (u16*)p;      p += (size_t)16384 * 512 * 2;        // 16.78 MB
  u16* Wbf = (u16*)p;     p += (size_t)2 * 2 * 1024 * 512 * 2; // 4.19 MB
  u16* G = (u16*)p;       p += (size_t)16384 * 2048 * 2;       // 67.1 MB
  u16* X1 = (u16*)p;      p += (size_t)16384 * 512 * 2;        // 16.78 MB
  u32* X2u = (u32*)p;     p += (size_t)16384 * 512 * 4;        // 33.55 MB
  float* out = (float*)d_out;

  // i8 Whh + per-row scales live in the X0 region's head, written AFTER gemm0
  // consumes X0 (X0 is dead from then on; gemm1 reads X1, rec1 writes X2u).
  signed char* Wq = (signed char*)X0;             // 4096 x 256 = 1 MB
  float* Wsc = (float*)((char*)X0 + 1048576);     // 4096 floats = 16 KB

  prep_k<<<16384, 64, 0, stream>>>(ids, amask, emb, X0);
  conv_k<<<1024, 256, 0, stream>>>(w_ih, Wbf, 262144);
  zero_k<<<1, 64, 0, stream>>>(out);
  // Layer 0
  gemm_k<<<dim3(256, 32), 256, 0, stream>>>(X0, Wbf, b_ih, b_hh, G);
  convw_k<<<4096, 64, 0, stream>>>(w_hh, Wq, Wsc);   // X0 dead after gemm0
  rec_k<<<16, 512, 0, stream>>>(G, Wq, Wsc, X1, nullptr);
  // Layer 1
  gemm_k<<<dim3(256, 32), 256, 0, stream>>>(X1, Wbf + 2 * 1024 * 512,
                                            b_ih + 2048, b_hh + 2048, G);
  rec_k<<<16, 512, 0, stream>>>(G, Wq + 2 * 262144, Wsc + 2048, nullptr, X2u);
  // Head + CRF
  head_k<<<16384, 64, 0, stream>>>(X2u, gamma, beta, cw, cb, out);
  crf_k<<<32, 64, 0, stream>>>(out + 1, labels, lens, tr, out);
}

// Round 11
// 1287.760 us; speedup vs baseline: 2.2074x; 1.1673x over previous
//
#include <hip/hip_runtime.h>

// Problem dims
#define B_ 32
#define S_ 512
#define D_ 512
#define H_ 256

typedef float floatx4 __attribute__((ext_vector_type(4)));
typedef short short8v __attribute__((ext_vector_type(8)));
typedef int intx4 __attribute__((ext_vector_type(4)));
typedef unsigned short u16;
typedef unsigned int u32;
typedef unsigned long long u64;

#define WS_NEEDED 138575872ull

__device__ __forceinline__ u16 f2bf(float f) {
  u32 x = __float_as_uint(f);
  x += 0x7fffu + ((x >> 16) & 1u);   // RNE
  return (u16)(x >> 16);
}
__device__ __forceinline__ float bf2f(u16 h) {
  return __uint_as_float(((u32)h) << 16);
}
__device__ __forceinline__ float decode_hl(u32 v) {
  return bf2f((u16)(v >> 16)) + bf2f((u16)(v & 0xffffu));
}
__device__ __forceinline__ float sigf(float x) {
  return 1.0f / (1.0f + __expf(-x));
}
__device__ __forceinline__ float tanh_f(float x) {
  float e = __expf(-2.0f * fabsf(x));
  float r = (1.0f - e) / (1.0f + e);
  return copysignf(r, x);
}
// fast reciprocal: single v_rcp_f32 (~1 ulp) instead of the ~11-op IEEE div
// expansion. Error ~1e-7 relative — invisible under the i8-quant noise.
__device__ __forceinline__ float rcp_f(float x) {
  float r; asm("v_rcp_f32 %0, %1" : "=v"(r) : "v"(x)); return r;
}
__device__ __forceinline__ float sig_fast(float x) {
  return rcp_f(1.0f + __expf(-x));
}
__device__ __forceinline__ float tanh_fast(float x) {
  float e = __expf(-2.0f * fabsf(x));
  float r = (1.0f - e) * rcp_f(1.0f + e);
  return copysignf(r, x);
}
// compile-time-indexed element select (rule #20: no runtime vector indexing)
__device__ __forceinline__ int sel4(intx4 v, int r) {
  const int lo = (r & 1) ? v[1] : v[0];
  const int hi = (r & 1) ? v[3] : v[2];
  return (r & 2) ? hi : lo;
}

struct alignas(16) U16x8 { u16 v[8]; };

// ---------------- embedding -> X0 bf16, time-major (m = s*32+b, 512 feats) ----------------
__global__ void prep_k(const int* __restrict__ ids, const int* __restrict__ amask,
                       const float* __restrict__ emb, u16* __restrict__ X0) {
  int m = blockIdx.x;            // m = s*32 + b
  int lane = threadIdx.x;        // 64
  int s = m >> 5, b = m & 31;
  int id = ids[b * S_ + s];
  int mk = amask[b * S_ + s];
  const float4* src = (const float4*)(emb + (size_t)id * D_) + lane * 2;
  float4 v0 = src[0], v1 = src[1];
  if (!mk) { v0 = make_float4(0,0,0,0); v1 = make_float4(0,0,0,0); }
  U16x8 o;
  o.v[0]=f2bf(v0.x); o.v[1]=f2bf(v0.y); o.v[2]=f2bf(v0.z); o.v[3]=f2bf(v0.w);
  o.v[4]=f2bf(v1.x); o.v[5]=f2bf(v1.y); o.v[6]=f2bf(v1.z); o.v[7]=f2bf(v1.w);
  *(U16x8*)(X0 + (size_t)m * D_ + lane * 8) = o;
}

// ---------------- fp32 -> bf16 weight convert (w_ih, 2*2*1024*512 elems) ----------------
__global__ void conv_k(const float* __restrict__ w, u16* __restrict__ wbf, int n8) {
  int idx = blockIdx.x * blockDim.x + threadIdx.x;
  if (idx >= n8) return;
  const float4* s = (const float4*)w + (size_t)idx * 2;
  float4 v0 = s[0], v1 = s[1];
  U16x8 o;
  o.v[0]=f2bf(v0.x); o.v[1]=f2bf(v0.y); o.v[2]=f2bf(v0.z); o.v[3]=f2bf(v0.w);
  o.v[4]=f2bf(v1.x); o.v[5]=f2bf(v1.y); o.v[6]=f2bf(v1.z); o.v[7]=f2bf(v1.w);
  *(U16x8*)(wbf + (size_t)idx * 8) = o;
}

// ---------------- zero loss ----------------
__global__ void zero_k(float* __restrict__ loss) {
  if (threadIdx.x == 0) *loss = 0.f;
}

// ---------------- w_hh fp32 -> per-row-scaled i8 (4096 rows of 256) ----------------
// w = s_row*q, q=rint(w/s_row) in [-127,127]; wsc[r] = s_row/127 (h's 1/127 folded in):
// gate_rec = sum(w*h) ~ wsc[r] * sum(qw*qh) with qh = rint(h*127).
__global__ void convw_k(const float* __restrict__ whh, signed char* __restrict__ wq,
                        float* __restrict__ wsc) {
  const int r = blockIdx.x;          // 0..4095 = (layer,dir,gate-row)
  const int lane = threadIdx.x;      // 64
  float4 v = *(const float4*)(whh + (size_t)r * 256 + lane * 4);
  float m = fmaxf(fmaxf(fabsf(v.x), fabsf(v.y)), fmaxf(fabsf(v.z), fabsf(v.w)));
  #pragma unroll
  for (int off = 32; off > 0; off >>= 1) m = fmaxf(m, __shfl_xor(m, off, 64));
  const float s = fmaxf(m, 1e-20f) * (1.0f / 127.0f);
  const float inv = 1.0f / s;
  int q0 = (int)rintf(v.x * inv), q1 = (int)rintf(v.y * inv);
  int q2 = (int)rintf(v.z * inv), q3 = (int)rintf(v.w * inv);
  u32 pk = (u32)(q0 & 255) | ((u32)(q1 & 255) << 8)
         | ((u32)(q2 & 255) << 16) | ((u32)(q3 & 255) << 24);
  *(u32*)(wq + (size_t)r * 256 + lane * 4) = pk;
  if (lane == 0) wsc[r] = s * (1.0f / 127.0f);
}

// ---------------- bf16 MFMA GEMM: G[m][n] = A[m][:] . W[n][:] + bih[n] + bhh[n] ----------------
__global__ void gemm_k(const u16* __restrict__ A, const u16* __restrict__ W,
                       const float* __restrict__ bih, const float* __restrict__ bhh,
                       u16* __restrict__ G) {
  __shared__ short Asm[64 * 40];
  __shared__ short Bsm[64 * 40];
  const int tid = threadIdx.x;
  const int m0 = blockIdx.x * 64, n0 = blockIdx.y * 64;
  const int wid = tid >> 6, lane = tid & 63;
  const int quad = lane >> 4, lr = lane & 15;
  const int wm = (wid >> 1) * 32, wn = (wid & 1) * 32;
  const int lrow = tid >> 2, lk = (tid & 3) * 8;
  floatx4 acc00 = {0,0,0,0}, acc01 = {0,0,0,0}, acc10 = {0,0,0,0}, acc11 = {0,0,0,0};
  for (int kt = 0; kt < 16; ++kt) {
    const int k0 = kt * 32;
    uint4 av = *(const uint4*)(A + (size_t)(m0 + lrow) * 512 + k0 + lk);
    uint4 bv = *(const uint4*)(W + (size_t)(n0 + lrow) * 512 + k0 + lk);
    __syncthreads();
    *(uint4*)&Asm[lrow * 40 + lk] = av;
    *(uint4*)&Bsm[lrow * 40 + lk] = bv;
    __syncthreads();
    short8v a0 = *(const short8v*)&Asm[(wm + lr) * 40 + quad * 8];
    short8v a1 = *(const short8v*)&Asm[(wm + 16 + lr) * 40 + quad * 8];
    short8v b0 = *(const short8v*)&Bsm[(wn + lr) * 40 + quad * 8];
    short8v b1 = *(const short8v*)&Bsm[(wn + 16 + lr) * 40 + quad * 8];
    acc00 = __builtin_amdgcn_mfma_f32_16x16x32_bf16(a0, b0, acc00, 0, 0, 0);
    acc01 = __builtin_amdgcn_mfma_f32_16x16x32_bf16(a0, b1, acc01, 0, 0, 0);
    acc10 = __builtin_amdgcn_mfma_f32_16x16x32_bf16(a1, b0, acc10, 0, 0, 0);
    acc11 = __builtin_amdgcn_mfma_f32_16x16x32_bf16(a1, b1, acc11, 0, 0, 0);
  }
  #pragma unroll
  for (int j = 0; j < 2; ++j) {
    const int n = n0 + wn + j * 16 + lr;
    const float bias = bih[n] + bhh[n];
    #pragma unroll
    for (int i = 0; i < 2; ++i) {
      const int mb = m0 + wm + i * 16 + quad * 4;
      floatx4 av = (i == 0) ? (j == 0 ? acc00 : acc01) : (j == 0 ? acc10 : acc11);
      #pragma unroll
      for (int rr = 0; rr < 4; ++rr) {
        G[(size_t)(mb + rr) * 2048 + n] = f2bf(av[rr] + bias);
      }
    }
  }
}

// ---------------- LSTM recurrence: block-local, 32 blocks, MFMA-floor bound ----------------
// v11 = v10 with one more batch split: 32 BLOCKS x 2 BATCHES, 1 CELL/LANE.
// Measured v10: MFMA issue/SIMD-step ~1300cy (invariant: every block streams
// the full Whh), VALU ~1700cy (2 cells/lane) -> VALU-bound at 2606cy/step.
// Halving cells/lane pushes VALU (~450-500cy/SIMD incl. 10 quarter-rate
// transcendentals/cell) BELOW the MFMA floor -> step becomes MFMA-issue-bound.
// Col map: c -> batch c&1, sub s=(c>>1)&1, reg r=c>>2 (bijective 2x2x4=16).
// Element select by runtime r uses compile-time-indexed cndmask (rule #20).
// h-store = one ds byte-write/lane (4-way byte-merge per dword, ~free).
// Everything else (swizzled hq, raw lgkm-only barrier, 2-deep G prefetch,
// direct X store) = v10-proven. Per-cell arithmetic identical -> same absmax.
__launch_bounds__(512, 2)
__global__ void rec_k(const u16* __restrict__ G, const signed char* __restrict__ wq_l,
                      const float* __restrict__ wsc_l,
                      u16* __restrict__ Xbf, u32* __restrict__ Xu) {
  __shared__ alignas(16) signed char hq[2][2][256];  // [parity][batch][k], swizzled 16B chunks

  const int tid = threadIdx.x;
  const int dir = blockIdx.x >> 4;
  const int bg = blockIdx.x & 15;  // 16 groups x 2 batches
  const int w = tid >> 6;          // wave = hidden chunk w*32
  const int lane = tid & 63;
  const int q = lane >> 4;
  const int c = lane & 15;         // MFMA column
  const int b2 = c & 1;            // batch in group (cols duplicate batches 8x)
  const int s = (c >> 1) & 1;      // sub-tile for this lane's cell
  const int r = c >> 2;            // reg (row within quad) of this lane's cell

  const signed char* wq = wq_l + (size_t)dir * 262144;
  const float* wsc = wsc_l + (size_t)dir * 1024;

  // ---- one-time: A-fragments (i8 weights, v8-proven layout) ----
  intx4 A[4][2][4];   // [gate][sub][ktile]
  #pragma unroll
  for (int g = 0; g < 4; ++g)
    #pragma unroll
    for (int s_ = 0; s_ < 2; ++s_) {
      const int row = g * 256 + w * 32 + s_ * 16 + c;
      #pragma unroll
      for (int kt = 0; kt < 4; ++kt)
        A[g][s_][kt] = *(const intx4*)(wq + (size_t)row * 256 + kt * 64 + q * 16);
    }
  // this lane's single cell: hidden = w*32 + s*16 + q*4 + r, batch b2
  const int hid = w * 32 + s * 16 + q * 4 + r;
  float sc[4];
  #pragma unroll
  for (int g = 0; g < 4; ++g) sc[g] = wsc[g * 256 + hid];

  if (tid < 64) ((uint4*)hq)[tid] = make_uint4(0, 0, 0, 0);  // 1 KB zero
  float cst = 0.f;

  // G for this lane's cell: 4 gates x 1 hidden, batch b2
  const u16* gb_ = G + (size_t)(bg * 2 + b2) * 2048 + dir * 1024 + hid;
  // 2-deep G prefetch (consumed 2 raw-barriers after issue; never drained early)
  u16 gc[4], gn[4];
  #pragma unroll
  for (int pf = 0; pf < 2; ++pf) {
    const int tn = dir ? (511 - pf) : pf;
    const u16* gp = gb_ + (size_t)tn * 65536;
    u16* dst = pf ? gn : gc;
    dst[0] = gp[0];
    dst[1] = gp[256];
    dst[2] = gp[512];
    dst[3] = gp[768];
  }
  __syncthreads();   // preamble only (full drain once is fine)

  for (int st = 0; st < 512; ++st) {
    const int par = st & 1;
    // B-fragments: batch row b2, data chunk j = kt*4+q stored at (j^b2)*16.
    // 8 lanes per address -> LDS broadcast; the two addresses hit disjoint banks.
    const signed char* hrow = &hq[par][b2][0];
    intx4 bf0 = *(const intx4*)&hrow[((0 * 4 + q) ^ b2) * 16];
    intx4 bf1 = *(const intx4*)&hrow[((1 * 4 + q) ^ b2) * 16];
    intx4 bf2 = *(const intx4*)&hrow[((2 * 4 + q) ^ b2) * 16];
    intx4 bf3 = *(const intx4*)&hrow[((3 * 4 + q) ^ b2) * 16];
    // MFMA: acc[g][s_] col c = gate g, sub-tile s_, batch c&1 (duplicated cols)
    intx4 acc[4][2];
    #pragma unroll
    for (int g = 0; g < 4; ++g)
      #pragma unroll
      for (int s_ = 0; s_ < 2; ++s_) {
        intx4 a_ = {0, 0, 0, 0};
        a_ = __builtin_amdgcn_mfma_i32_16x16x64_i8(A[g][s_][0], bf0, a_, 0, 0, 0);
        a_ = __builtin_amdgcn_mfma_i32_16x16x64_i8(A[g][s_][1], bf1, a_, 0, 0, 0);
        a_ = __builtin_amdgcn_mfma_i32_16x16x64_i8(A[g][s_][2], bf2, a_, 0, 0, 0);
        a_ = __builtin_amdgcn_mfma_i32_16x16x64_i8(A[g][s_][3], bf3, a_, 0, 0, 0);
        acc[g][s_] = a_;
      }
    // select this lane's sub-tile + element (compile-time indices only)
    const int v0 = sel4(s ? acc[0][1] : acc[0][0], r);
    const int v1 = sel4(s ? acc[1][1] : acc[1][0], r);
    const int v2 = sel4(s ? acc[2][1] : acc[2][0], r);
    const int v3 = sel4(s ? acc[3][1] : acc[3][0], r);
    // cell update: ONE cell per lane, fast-rcp transcendentals
    const float si = bf2f(gc[0]) + (float)v0 * sc[0];
    const float sf = bf2f(gc[1]) + (float)v1 * sc[1];
    const float sg = bf2f(gc[2]) + (float)v2 * sc[2];
    const float so = bf2f(gc[3]) + (float)v3 * sc[3];
    const float ig = sig_fast(si), fg = sig_fast(sf);
    const float gg = tanh_fast(sg), og = sig_fast(so);
    const float cn = fg * cst + ig * gg;
    const float hn = og * tanh_fast(cn);
    cst = cn;
    const u16 hb = f2bf(hn);
    // quantize h -> i8, one swizzled byte write (4 lanes/dword byte-merge)
    {
      const int qv = (int)rintf(hn * 127.f);
      const int chunk = 2 * w + s;             // 16B data-chunk index
      ((signed char*)hq)[(size_t)(par ^ 1) * 512 + b2 * 256
                         + ((chunk ^ b2) * 16) + q * 4 + r] = (signed char)qv;
    }
    // X output: direct global write (floats across the raw barrier freely)
    {
      const int tt = dir ? (511 - st) : st;
      const size_t xo = ((size_t)tt * 32 + bg * 2 + b2) * 512 + dir * 256 + hid;
      if (Xbf) {
        *(u16*)(Xbf + xo) = hb;
      } else {
        *(u32*)(Xu + xo) = ((u32)hb << 16) | f2bf(hn - bf2f(hb));
      }
    }
    // rotate G pipeline: consume st (gc), promote gn, issue st+2
    gc[0] = gn[0]; gc[1] = gn[1]; gc[2] = gn[2]; gc[3] = gn[3];
    {
      const int stn = (st + 2 < 512) ? st + 2 : 511;
      const int tn = dir ? (511 - stn) : stn;
      const u16* gp = gb_ + (size_t)tn * 65536;
      gn[0] = gp[0];
      gn[1] = gp[256];
      gn[2] = gp[512];
      gn[3] = gp[768];
    }
    // raw barrier: LDS-drain only, NO vmcnt drain (G/X stay in flight)
    asm volatile("s_waitcnt lgkmcnt(0)" ::: "memory");
    __builtin_amdgcn_s_barrier();
    __builtin_amdgcn_sched_barrier(0);
  }
}

// ---------------- LayerNorm + classifier head; logits -> d_out+1 ----------------
// X2u: packed (bf16hi<<16|bf16lo) per element; decode = bf2f(hi)+bf2f(lo)
__global__ void head_k(const u32* __restrict__ X2u, const float* __restrict__ gamma,
                       const float* __restrict__ beta, const float* __restrict__ cw,
                       const float* __restrict__ cb, float* __restrict__ out) {
  __shared__ float red[9][64];
  const int m = blockIdx.x, lane = threadIdx.x;
  const int s = m >> 5, b = m & 31;
  const uint4* xp = (const uint4*)(X2u + (size_t)m * 512) + lane * 2;
  uint4 a0 = xp[0], a1 = xp[1];
  float x[8];
  x[0] = decode_hl(a0.x); x[1] = decode_hl(a0.y);
  x[2] = decode_hl(a0.z); x[3] = decode_hl(a0.w);
  x[4] = decode_hl(a1.x); x[5] = decode_hl(a1.y);
  x[6] = decode_hl(a1.z); x[7] = decode_hl(a1.w);
  float sm = 0.f, sq = 0.f;
  #pragma unroll
  for (int i = 0; i < 8; ++i) { sm += x[i]; sq += x[i] * x[i]; }
  #pragma unroll
  for (int off = 32; off > 0; off >>= 1) {
    sm += __shfl_xor(sm, off, 64);
    sq += __shfl_xor(sq, off, 64);
  }
  const float mu = sm * (1.0f / 512.0f);
  const float var = sq * (1.0f / 512.0f) - mu * mu;
  const float rs = rsqrtf(var + 1e-5f);
  const float4* gp = (const float4*)gamma + lane * 2;
  const float4* bp = (const float4*)beta + lane * 2;
  float4 g0 = gp[0], g1 = gp[1], be0 = bp[0], be1 = bp[1];
  float nv[8];
  nv[0] = (x[0] - mu) * rs * g0.x + be0.x;
  nv[1] = (x[1] - mu) * rs * g0.y + be0.y;
  nv[2] = (x[2] - mu) * rs * g0.z + be0.z;
  nv[3] = (x[3] - mu) * rs * g0.w + be0.w;
  nv[4] = (x[4] - mu) * rs * g1.x + be1.x;
  nv[5] = (x[5] - mu) * rs * g1.y + be1.y;
  nv[6] = (x[6] - mu) * rs * g1.z + be1.z;
  nv[7] = (x[7] - mu) * rs * g1.w + be1.w;
  #pragma unroll
  for (int c = 0; c < 9; ++c) {
    const float4* wp = (const float4*)(cw + (size_t)c * 512) + lane * 2;
    float4 w0 = wp[0], w1 = wp[1];
    red[c][lane] = nv[0]*w0.x + nv[1]*w0.y + nv[2]*w0.z + nv[3]*w0.w
                 + nv[4]*w1.x + nv[5]*w1.y + nv[6]*w1.z + nv[7]*w1.w;
  }
  __syncthreads();
  if (lane < 9) {
    float t = 0.f;
    for (int i = 0; i < 64; ++i) t += red[lane][i];
    out[1 + ((size_t)b * 512 + s) * 9 + lane] = t + cb[lane];
  }
}

// ---------------- CRF NLL: one wave per batch element ----------------
__global__ void crf_k(const float* __restrict__ logits, const int* __restrict__ labels,
                      const int* __restrict__ lens, const float* __restrict__ tr,
                      float* __restrict__ loss) {
  const int b = blockIdx.x, lane = threadIdx.x;
  const int len = lens[b];
  float trj[9];
  #pragma unroll
  for (int i = 0; i < 9; ++i) trj[i] = 0.f;
  if (lane < 9) {
    #pragma unroll
    for (int i = 0; i < 9; ++i) trj[i] = tr[i * 11 + lane];
  }
  float alpha = -1e30f;
  if (lane < 9) alpha = tr[9 * 11 + lane] + logits[(size_t)b * 512 * 9 + lane];
  for (int t = 1; t < len; ++t) {
    float e = (lane < 9) ? logits[((size_t)b * 512 + t) * 9 + lane] : 0.f;
    float v[9];
    float mx = -1e30f;
    #pragma unroll
    for (int i = 0; i < 9; ++i) {
      v[i] = __shfl(alpha, i, 64) + trj[i];
      mx = fmaxf(mx, v[i]);
    }
    float ss = 0.f;
    #pragma unroll
    for (int i = 0; i < 9; ++i) ss += __expf(v[i] - mx);
    float na = mx + __logf(ss) + e;
    if (lane < 9) alpha = na;
  }
  float fin = (lane < 9) ? alpha + tr[lane * 11 + 10] : -1e30f;
  float mx = fin;
  #pragma unroll
  for (int off = 8; off > 0; off >>= 1) mx = fmaxf(mx, __shfl_xor(mx, off, 64));
  float es = (lane < 9) ? __expf(fin - mx) : 0.f;
  #pragma unroll
  for (int off = 8; off > 0; off >>= 1) es += __shfl_xor(es, off, 64);
  const float logZ = mx + __logf(es);
  float emit = 0.f, ts = 0.f;
  for (int t = lane; t < len; t += 64) {
    int y = labels[b * 512 + t];
    emit += logits[((size_t)b * 512 + t) * 9 + y];
  }
  for (int t = 1 + lane; t < len; t += 64) {
    int y0 = labels[b * 512 + t - 1], y1 = labels[b * 512 + t];
    ts += tr[y0 * 11 + y1];
  }
  #pragma unroll
  for (int off = 32; off > 0; off >>= 1) {
    emit += __shfl_xor(emit, off, 64);
    ts += __shfl_xor(ts, off, 64);
  }
  if (lane == 0) {
    int y0 = labels[b * 512], yl = labels[b * 512 + len - 1];
    float gold = emit + ts + tr[9 * 11 + y0] + tr[yl * 11 + 10];
    atomicAdd(loss, (logZ - gold) * (1.0f / 32.0f));
  }
}

extern "C" void kernel_launch(void* const* d_in, const int* in_sizes, int n_in,
                              void* d_out, int out_size, void* d_ws, size_t ws_size,
                              hipStream_t stream) {
  const int* ids = (const int*)d_in[0];
  const int* amask = (const int*)d_in[1];
  const int* lens = (const int*)d_in[2];
  const int* labels = (const int*)d_in[3];
  const float* emb = (const float*)d_in[4];
  const float* w_ih = (const float*)d_in[5];
  const float* w_hh = (const float*)d_in[6];
  const float* b_ih = (const float*)d_in[7];
  const float* b_hh = (const float*)d_in[8];
  const float* gamma = (const float*)d_in[9];
  const float* beta = (const float*)d_in[10];
  const float* cw = (const float*)d_in[11];
  const float* cb = (const float*)d_in[12];
  const float* tr = (const float*)d_in[13];
  (void)in_sizes; (void)n_in; (void)out_size;

  if (ws_size < WS_NEEDED) return;  // workspace too small -> clean failure

  char* p = (char*)d_ws;
  u16* X0 = (u16*)p;      p += (size_t)16384 * 512 * 2;        // 16.78 MB
  u16* Wbf = (u16*)p;     p += (size_t)2 * 2 * 1024 * 512 * 2; // 4.19 MB
  u16* G = (u16*)p;       p += (size_t)16384 * 2048 * 2;       // 67.1 MB
  u16* X1 = (u16*)p;      p += (size_t)16384 * 512 * 2;        // 16.78 MB
  u32* X2u = (u32*)p;     p += (size_t)16384 * 512 * 4;        // 33.55 MB
  float* out = (float*)d_out;

  // i8 Whh + per-row scales live in the X0 region's head, written AFTER gemm0
  // consumes X0 (X0 is dead from then on; gemm1 reads X1, rec1 writes X2u).
  signed char* Wq = (signed char*)X0;             // 4096 x 256 = 1 MB
  float* Wsc = (float*)((char*)X0 + 1048576);     // 4096 floats = 16 KB

  prep_k<<<16384, 64, 0, stream>>>(ids, amask, emb, X0);
  conv_k<<<1024, 256, 0, stream>>>(w_ih, Wbf, 262144);
  zero_k<<<1, 64, 0, stream>>>(out);
  // Layer 0
  gemm_k<<<dim3(256, 32), 256, 0, stream>>>(X0, Wbf, b_ih, b_hh, G);
  convw_k<<<4096, 64, 0, stream>>>(w_hh, Wq, Wsc);   // X0 dead after gemm0
  rec_k<<<32, 512, 0, stream>>>(G, Wq, Wsc, X1, nullptr);
  // Layer 1
  gemm_k<<<dim3(256, 32), 256, 0, stream>>>(X1, Wbf + 2 * 1024 * 512,
                                            b_ih + 2048, b_hh + 2048, G);
  rec_k<<<32, 512, 0, stream>>>(G, Wq + 2 * 262144, Wsc + 2048, nullptr, X2u);
  // Head + CRF
  head_k<<<16384, 64, 0, stream>>>(X2u, gamma, beta, cw, cb, out);
  crf_k<<<32, 64, 0, stream>>>(out + 1, labels, lens, tr, out);
}